// Round 3
// baseline (423.093 us; speedup 1.0000x reference)
//
#include <hip/hip_runtime.h>
#include <hip/hip_bf16.h>
#include <math.h>

typedef unsigned short u16;
typedef __attribute__((ext_vector_type(8))) __bf16 bf16x8;
typedef __attribute__((ext_vector_type(4))) float floatx4;

#define SEQ   4096
#define BATCH 8
#define ROWS  32768   // BATCH*SEQ
#define C     512
#define NH    16
#define HD    32

__device__ inline u16 f2bf(float f) {
    union { float f; unsigned u; } v; v.f = f;
    unsigned r = (v.u + 0x7FFFu + ((v.u >> 16) & 1u)) >> 16;
    return (u16)r;
}
__device__ inline float bf2f(u16 h) {
    union { unsigned u; float f; } v; v.u = ((unsigned)h) << 16;
    return v.f;
}

// async global -> LDS, 16B per lane; lds ptr must be wave-uniform (HW adds lane*16)
__device__ inline void g2lds16(const u16* g, u16* l) {
    __builtin_amdgcn_global_load_lds((const __attribute__((address_space(1))) unsigned*)g,
                                     (__attribute__((address_space(3))) unsigned*)l, 16, 0, 0);
}

// ---------------- weight prep: fp32 (k,n) -> bf16 transposed (n,k), 64x64 LDS tiles ----------------
__global__ __launch_bounds__(256) void prep_weights(
    const float* __restrict__ Wq, const float* __restrict__ Wk,
    const float* __restrict__ Wv, const float* __restrict__ Wm,
    const float* __restrict__ W1, const float* __restrict__ W2,
    u16* __restrict__ Wqkvt, u16* __restrict__ Wmt,
    u16* __restrict__ W1t, u16* __restrict__ W2t)
{
    int blk = blockIdx.x;                 // 6 mats * 64 tiles
    int mat = blk >> 6;
    int tile = blk & 63;
    int k0 = (tile >> 3) * 64, n0 = (tile & 7) * 64;
    const float* src; u16* dst;
    switch (mat) {
        case 0: src = Wq; dst = Wqkvt;              break;
        case 1: src = Wk; dst = Wqkvt + 512*512;    break;
        case 2: src = Wv; dst = Wqkvt + 2*512*512;  break;
        case 3: src = Wm; dst = Wmt;                break;
        case 4: src = W1; dst = W1t;                break;
        default: src = W2; dst = W2t;               break;
    }
    __shared__ float ts[64][65];
    int t = threadIdx.x;
    #pragma unroll
    for (int i = 0; i < 16; i++) {
        int e = i * 256 + t;
        int kr = e >> 6, nc = e & 63;
        ts[kr][nc] = src[(size_t)(k0 + kr) * 512 + n0 + nc];   // coalesced 256B rows
    }
    __syncthreads();
    #pragma unroll
    for (int i = 0; i < 2; i++) {
        int e = i * 256 + t;                 // 512 chunks of 8
        int nr = e >> 3, kc0 = (e & 7) * 8;
        union { uint4 v; u16 u[8]; } o;
        #pragma unroll
        for (int q = 0; q < 8; q++) o.u[q] = f2bf(ts[kc0 + q][nr]);
        *(uint4*)(dst + (size_t)(n0 + nr) * 512 + k0 + kc0) = o.v;   // coalesced 16B stores
    }
}

// ---------------- layernorm: fp32 in -> bf16 out, one wave per row ----------------
__global__ __launch_bounds__(256) void ln_kernel(
    const float* __restrict__ in, const float* __restrict__ g,
    const float* __restrict__ b, u16* __restrict__ out)
{
    int row  = blockIdx.x * 4 + (threadIdx.x >> 6);
    int lane = threadIdx.x & 63;
    const float* p = in + (size_t)row * C + lane * 8;
    float4 v0 = *(const float4*)p;
    float4 v1 = *(const float4*)(p + 4);
    float s  = v0.x + v0.y + v0.z + v0.w + v1.x + v1.y + v1.z + v1.w;
    float s2 = v0.x*v0.x + v0.y*v0.y + v0.z*v0.z + v0.w*v0.w
             + v1.x*v1.x + v1.y*v1.y + v1.z*v1.z + v1.w*v1.w;
    #pragma unroll
    for (int off = 1; off < 64; off <<= 1) {
        s  += __shfl_xor(s, off);
        s2 += __shfl_xor(s2, off);
    }
    float mean = s * (1.f / C);
    float var  = s2 * (1.f / C) - mean * mean;
    float inv  = rsqrtf(var + 1e-6f);
    int c = lane * 8;
    float4 g0 = *(const float4*)(g + c), g1 = *(const float4*)(g + c + 4);
    float4 b0 = *(const float4*)(b + c), b1 = *(const float4*)(b + c + 4);
    union { uint4 v; u16 u[8]; } o;
    o.u[0] = f2bf((v0.x - mean) * inv * g0.x + b0.x);
    o.u[1] = f2bf((v0.y - mean) * inv * g0.y + b0.y);
    o.u[2] = f2bf((v0.z - mean) * inv * g0.z + b0.z);
    o.u[3] = f2bf((v0.w - mean) * inv * g0.w + b0.w);
    o.u[4] = f2bf((v1.x - mean) * inv * g1.x + b1.x);
    o.u[5] = f2bf((v1.y - mean) * inv * g1.y + b1.y);
    o.u[6] = f2bf((v1.z - mean) * inv * g1.z + b1.z);
    o.u[7] = f2bf((v1.w - mean) * inv * g1.w + b1.w);
    *(uint4*)(out + (size_t)row * C + c) = o.v;
}

// ---------------- bf16 MFMA GEMM, 256x256 tile, 8-phase counted-vmcnt schedule ----------------
// K fixed at 512. BM=BN=256, BK=64, 8 waves (2M x 4N), 512 threads, 128 KiB LDS.
// R2 fix (kept): 8 DISTINCT __shared__ arrays so the waitcnt pass can prove ds_reads don't
// alias in-flight LDS-DMA and emits precise counted waits instead of drains.
// R3 fix: waitcnt inline asm must NOT carry a "memory" clobber. SIInsertWaitcnts treats a
// clobbered INLINEASM as an unknown memory op and inserts s_waitcnt vmcnt(0) BEFORE it --
// two forced drains per phase (measured: 1700cy/phase, MfmaUtil 25%, = the 2-phase-drain
// structure). Clobber-free asm + sched_barrier(0) pins (rule #18) is the verified recipe.
// Stage schedule per iter (2 loads each):
//   ph0: A1h1<-k+64   ph1: B1h0<-k+64   ph2: A0h0<-k+128  ph3: B0h1<-k+128 [vmcnt(4)]
//   ph4: A0h1<-k+128  ph5: B0h0<-k+128  ph6: A1h0<-k+192  ph7: B1h1<-k+192 [vmcnt(4)]
// vmcnt(4) before the mid-phase barrier => all waves' slab loads landed after the barrier.
// Never drains to 0 in the main loop; tail peeled with one vmcnt(0).

#define STG2(ARR, GBASE, KC)                                                    \
  do {                                                                          \
    const u16* _g = (GBASE) + (KC);                                             \
    u16* _l = (ARR) + w * 1024;                                                 \
    g2lds16(_g, _l);                                                            \
    g2lds16(_g + 8 * 512, _l + 512);                                            \
  } while (0)

#define RDA(ARR)                                                                \
  do {                                                                          \
    const u16* As_ = (ARR) + aoff;                                              \
    _Pragma("unroll") for (int ii = 0; ii < 4; ii++) {                          \
      af0[ii] = *(const bf16x8*)(As_ + ii * 1024 + ck0);                        \
      af1[ii] = *(const bf16x8*)(As_ + ii * 1024 + ck1);                        \
    }                                                                           \
  } while (0)

#define RDB(ARR)                                                                \
  do {                                                                          \
    const u16* Bs_ = (ARR) + boff;                                              \
    _Pragma("unroll") for (int jj = 0; jj < 2; jj++) {                          \
      bv0[jj] = *(const bf16x8*)(Bs_ + jj * 1024 + ck0);                        \
      bv1[jj] = *(const bf16x8*)(Bs_ + jj * 1024 + ck1);                        \
    }                                                                           \
  } while (0)

#define PHX(MH, NHI, STG, VM)                                                   \
  do {                                                                          \
    STG;                                                                        \
    __builtin_amdgcn_sched_barrier(0);                                          \
    if constexpr ((VM) == 4) asm volatile("s_waitcnt vmcnt(4)");                \
    else if constexpr ((VM) == 0) asm volatile("s_waitcnt vmcnt(0)");           \
    __builtin_amdgcn_s_barrier();                                               \
    asm volatile("s_waitcnt lgkmcnt(0)");                                       \
    __builtin_amdgcn_sched_barrier(0);                                          \
    __builtin_amdgcn_s_setprio(1);                                              \
    _Pragma("unroll") for (int ii = 0; ii < 4; ii++)                            \
      _Pragma("unroll") for (int jj = 0; jj < 2; jj++) {                        \
        acc[(MH)*4+ii][(NHI)*2+jj] = __builtin_amdgcn_mfma_f32_16x16x32_bf16(   \
            af0[ii], bv0[jj], acc[(MH)*4+ii][(NHI)*2+jj], 0, 0, 0);             \
        acc[(MH)*4+ii][(NHI)*2+jj] = __builtin_amdgcn_mfma_f32_16x16x32_bf16(   \
            af1[ii], bv1[jj], acc[(MH)*4+ii][(NHI)*2+jj], 0, 0, 0);             \
      }                                                                         \
    __builtin_amdgcn_s_setprio(0);                                              \
    __builtin_amdgcn_s_barrier();                                               \
    __builtin_amdgcn_sched_barrier(0);                                          \
  } while (0)

template <int EPI>
__global__ __launch_bounds__(512, 2) void gemm256(
    const u16* __restrict__ A, const u16* __restrict__ Bt,
    int ldc, int nx,
    u16* __restrict__ outb, float* __restrict__ outf,
    const float* __restrict__ bias, const float* __restrict__ resid)
{
    // 8 distinct LDS objects: [slab][half], each 128 rows x 64 cols bf16 = 16 KB
    __shared__ u16 A0h0[8192], A0h1[8192], A1h0[8192], A1h1[8192];
    __shared__ u16 B0h0[8192], B0h1[8192], B1h0[8192], B1h1[8192];

    const int t = threadIdx.x;
    const int w = t >> 6, l = t & 63, lr = l & 15, quad = l >> 4;
    const int wr = w >> 2, wc = w & 3;

    // grouped XCD swizzle: xcd g&7; within XCD sweep x-major over groups of 2 y-tiles
    const int g = blockIdx.x;
    const int xcd = g & 7;
    const int q = g >> 3;
    const int grp = q / (nx * 2), rem = q - grp * (nx * 2);
    const int tx = rem >> 1;
    const int ty = xcd * 16 + grp * 2 + (rem & 1);
    const int m0 = ty * 256, n0 = tx * 256;

    // staging addresses: wave w covers rows [w*16, w*16+16) of a 128-row half (2 loads)
    const int rh = w * 16 + (l >> 3);
    const int swz = (((l & 7) - (l >> 3)) & 7) * 8;   // rotated source chunk
    const u16* Ab0 = A  + (size_t)(m0 + rh) * 512 + swz;
    const u16* Bb0 = Bt + (size_t)(n0 + rh) * 512 + swz;
    const u16* Ab1 = Ab0 + (size_t)128 * 512;
    const u16* Bb1 = Bb0 + (size_t)128 * 512;

    // fragment read offsets (u16 units); row&7 == lr&7 -> physical chunk (m + lr)&7
    const int aoff = (wr * 64 + lr) * 64;
    const int boff = (wc * 32 + lr) * 64;
    const int ck0 = (((0 + quad + (lr & 7)) & 7) * 8);
    const int ck1 = (((4 + quad + (lr & 7)) & 7) * 8);

    floatx4 acc[8][4];
    #pragma unroll
    for (int i = 0; i < 8; i++)
        #pragma unroll
        for (int j = 0; j < 4; j++) { floatx4 z = {0.f, 0.f, 0.f, 0.f}; acc[i][j] = z; }

    bf16x8 af0[4], af1[4], bv0[2], bv1[2];

    // prologue: slab0 <- tile0 (all 4 halves), slab1 <- tile1 {A-h0, B-h1}
    STG2(A0h0, Ab0, 0); STG2(A0h1, Ab1, 0); STG2(B0h0, Bb0, 0); STG2(B0h1, Bb1, 0);
    STG2(A1h0, Ab0, 64); STG2(B1h1, Bb1, 64);
    __builtin_amdgcn_sched_barrier(0);
    asm volatile("s_waitcnt vmcnt(4)");                // slab0's 8 landed
    __builtin_amdgcn_s_barrier();
    __builtin_amdgcn_sched_barrier(0);

    int kk = 0;
    for (int it = 0; it < 3; ++it, kk += 128) {        // K=512 -> 4 iters, last peeled
        RDA(A0h0); RDB(B0h0); PHX(0, 0, STG2(A1h1, Ab1, kk + 64),  -1);
        RDB(B0h1);            PHX(0, 1, STG2(B1h0, Bb0, kk + 64),  -1);
        RDA(A0h1);            PHX(1, 1, STG2(A0h0, Ab0, kk + 128), -1);
        RDB(B0h0);            PHX(1, 0, STG2(B0h1, Bb1, kk + 128),  4);
        RDA(A1h0); RDB(B1h0); PHX(0, 0, STG2(A0h1, Ab1, kk + 128), -1);
        RDB(B1h1);            PHX(0, 1, STG2(B0h0, Bb0, kk + 128), -1);
        RDA(A1h1);            PHX(1, 1, STG2(A1h0, Ab0, kk + 192), -1);
        RDB(B1h0);            PHX(1, 0, STG2(B1h1, Bb1, kk + 192),  4);
    }
    // tail (kk=384): slab0 holds 384; finish staging 448 into slab1; one vmcnt(0)
    RDA(A0h0); RDB(B0h0); PHX(0, 0, STG2(A1h1, Ab1, 448), -1);
    RDB(B0h1);            PHX(0, 1, STG2(B1h0, Bb0, 448), -1);
    RDA(A0h1);            PHX(1, 1, (void)0, -1);
    RDB(B0h0);            PHX(1, 0, (void)0,  0);
    RDA(A1h0); RDB(B1h0); PHX(0, 0, (void)0, -1);
    RDB(B1h1);            PHX(0, 1, (void)0, -1);
    RDA(A1h1);            PHX(1, 1, (void)0, -1);
    RDB(B1h0);            PHX(1, 0, (void)0, -1);

    // epilogue
    #pragma unroll
    for (int i = 0; i < 8; i++) {
        #pragma unroll
        for (int j = 0; j < 4; j++) {
            #pragma unroll
            for (int r = 0; r < 4; r++) {
                int row = m0 + (i >> 2) * 128 + wr * 64 + (i & 3) * 16 + quad * 4 + r;
                int col = n0 + (j >> 1) * 128 + wc * 32 + (j & 1) * 16 + lr;
                float v = acc[i][j][r];
                size_t idx = (size_t)row * ldc + col;
                if constexpr (EPI == 0) {
                    if (col < 1024) v = v > 0.f ? v + 1.f : __expf(v);
                    else            v *= (1.0f / SEQ);
                    outb[idx] = f2bf(v);
                } else if constexpr (EPI == 1) {
                    outf[idx] = resid[idx] + v;
                } else if constexpr (EPI == 2) {
                    v += bias[col];
                    v = 0.5f * v * (1.f + erff(v * 0.70710678118f));
                    outb[idx] = f2bf(v);
                } else {
                    outf[idx] = outf[idx] + v + bias[col];
                }
            }
        }
    }
}

// ---------------- KV partials via MFMA: per-wave private LDS tiles, no atomics ----------------
__global__ __launch_bounds__(256) void kv_reduce(
    const u16* __restrict__ qkv, float* __restrict__ Pkv, float* __restrict__ PKsum)
{
    const int bh = blockIdx.x;            // 0..127
    const int b = bh >> 4, h = bh & 15;
    const int chunk = blockIdx.y;         // 0..7
    const int t = threadIdx.x;
    const int w = t >> 6, l = t & 63, lr = l & 15, quad = l >> 4;
    __shared__ u16 lds[4 * 2 * 2048];     // [wave][buf][K 1024 | V 1024] = 32 KB

    const int sbase = chunk * 512 + w * 128;
    const u16* qbase = qkv + (size_t)b * SEQ * 1536 + 512 + h * HD;  // K part; V = +512

    const int sl0 = l >> 2;               // rows 0..15 (instr 0)
    const int sl1 = 16 + sl0;             // rows 16..31 (instr 1)
    const int cl  = l & 3;
    const int cg0 = (cl + (sl0 >> 3)) & 3;
    const int cg1 = (cl + (sl1 >> 3)) & 3;
    const int gof0 = sl0 * 1536 + cg0 * 8;
    const int gof1 = sl1 * 1536 + cg1 * 8;

    u16* myl = lds + w * 4096;

    const int offA0 = quad * 256 + ((((lr >> 3) + 0) - quad) & 3) * 8 + (lr & 7);  // d 0..15
    const int offA1 = quad * 256 + ((((lr >> 3) + 2) - quad) & 3) * 8 + (lr & 7);  // d 16..31

    floatx4 a00 = {0,0,0,0}, a01 = {0,0,0,0}, a10 = {0,0,0,0}, a11 = {0,0,0,0};
    float ks0 = 0.f, ks1 = 0.f;

    {
        const u16* gK = qbase + (size_t)sbase * 1536;
        g2lds16(gK + gof0,       myl);
        g2lds16(gK + gof1,       myl + 512);
        g2lds16(gK + 512 + gof0, myl + 1024);
        g2lds16(gK + 512 + gof1, myl + 1536);
    }
    #pragma unroll
    for (int st = 0; st < 4; st++) {
        if (st < 3) {                      // prefetch next buf before the drain
            const u16* gK = qbase + (size_t)(sbase + (st + 1) * 32) * 1536;
            u16* nl = myl + ((st + 1) & 1) * 2048;
            g2lds16(gK + gof0,       nl);
            g2lds16(gK + gof1,       nl + 512);
            g2lds16(gK + 512 + gof0, nl + 1024);
            g2lds16(gK + 512 + gof1, nl + 1536);
        }
        __syncthreads();                   // vmcnt(0) drain, compiler-safe fence
        const u16* lK = myl + (st & 1) * 2048;
        const u16* lV = lK + 1024;
        union { bf16x8 v; u16 u[8]; } fa0, fa1, fb0, fb1;
        #pragma unroll
        for (int j = 0; j < 8; j++) {
            fa0.u[j] = lK[offA0 + j * 32];
            fa1.u[j] = lK[offA1 + j * 32];
            fb0.u[j] = lV[offA0 + j * 32];
            fb1.u[j] = lV[offA1 + j * 32];
        }
        #pragma unroll
        for (int j = 0; j < 8; j++) { ks0 += bf2f(fa0.u[j]); ks1 += bf2f(fa1.u[j]); }
        a00 = __builtin_amdgcn_mfma_f32_16x16x32_bf16(fa0.v, fb0.v, a00, 0, 0, 0);
        a01 = __builtin_amdgcn_mfma_f32_16x16x32_bf16(fa0.v, fb1.v, a01, 0, 0, 0);
        a10 = __builtin_amdgcn_mfma_f32_16x16x32_bf16(fa1.v, fb0.v, a10, 0, 0, 0);
        a11 = __builtin_amdgcn_mfma_f32_16x16x32_bf16(fa1.v, fb1.v, a11, 0, 0, 0);
    }

    const int p = bh * 32 + chunk * 4 + w;
    float* dst = Pkv + (size_t)p * 1024;
    floatx4 accs[2][2] = {{a00, a01}, {a10, a11}};
    #pragma unroll
    for (int i = 0; i < 2; i++)
        #pragma unroll
        for (int j = 0; j < 2; j++)
            #pragma unroll
            for (int r = 0; r < 4; r++)
                dst[(i * 16 + quad * 4 + r) * 32 + j * 16 + lr] = accs[i][j][r];

    float k0 = ks0 + __shfl_xor(ks0, 16); k0 += __shfl_xor(k0, 32);
    float k1 = ks1 + __shfl_xor(ks1, 16); k1 += __shfl_xor(k1, 32);
    if (quad == 0) {
        PKsum[p * 32 + lr]      = k0;
        PKsum[p * 32 + 16 + lr] = k1;
    }
}

// ---------------- final reduce: KV[bh][1024] = sum of 32 partials; Ksum likewise ----------------
__global__ __launch_bounds__(256) void kv_final(
    const float* __restrict__ Pkv, const float* __restrict__ PKsum,
    float* __restrict__ KV, float* __restrict__ Ksum)
{
    const int bh = blockIdx.x;
    const int t = threadIdx.x;
    float a0 = 0.f, a1 = 0.f, a2 = 0.f, a3 = 0.f;
    for (int p = 0; p < 32; p++) {
        const float* src = Pkv + ((size_t)bh * 32 + p) * 1024;
        a0 += src[t];
        a1 += src[t + 256];
        a2 += src[t + 512];
        a3 += src[t + 768];
    }
    float* dst = KV + (size_t)bh * 1024;
    dst[t] = a0; dst[t + 256] = a1; dst[t + 512] = a2; dst[t + 768] = a3;
    if (t < 32) {
        float s = 0.f;
        for (int p = 0; p < 32; p++) s += PKsum[(bh * 32 + p) * 32 + t];
        Ksum[bh * 32 + t] = s;
    }
}

// ---------------- msg = (Q . KV) * SEQ / (Q . Ksum + eps) ----------------
__global__ __launch_bounds__(256) void msg_kernel(
    const u16* __restrict__ qkv, const float* __restrict__ KV,
    const float* __restrict__ Ksum, u16* __restrict__ msg)
{
    int blk = blockIdx.x;           // 1024 blocks
    int b = blk >> 7;
    int r0 = (blk & 127) * 32;
    int t = threadIdx.x;
    int h = t >> 4;
    int vd = (t & 15) * 2;
    float kv0[32], kv1[32], ksr[32];
    const float* kvh = KV + ((size_t)b * 16 + h) * 1024;
    const float* ksh = Ksum + (b * 16 + h) * 32;
    #pragma unroll
    for (int d = 0; d < 32; d++) {
        kv0[d] = kvh[d * 32 + vd];
        kv1[d] = kvh[d * 32 + vd + 1];
        ksr[d] = ksh[d];
    }
    __shared__ u16 Qs[4 * 512];
    const int srr = t >> 6;
    const int scc = (t & 63) * 8;
    for (int rg = 0; rg < 32; rg += 4) {
        size_t row = (size_t)b * SEQ + r0 + rg;
        uint4 qv = *(const uint4*)(qkv + (row + srr) * 1536 + scc);
        __syncthreads();
        *(uint4*)(Qs + srr * 512 + scc) = qv;
        __syncthreads();
        #pragma unroll
        for (int r2 = 0; r2 < 4; r2++) {
            const u16* qp = Qs + r2 * 512 + h * HD;
            float q[32];
            #pragma unroll
            for (int i0 = 0; i0 < 32; i0 += 8) {
                union { uint4 v; u16 u[8]; } uu;
                uu.v = *(const uint4*)(qp + i0);
                #pragma unroll
                for (int jq = 0; jq < 8; jq++) q[i0 + jq] = bf2f(uu.u[jq]);
            }
            float zdot = 0.f, m0 = 0.f, m1 = 0.f;
            #pragma unroll
            for (int d = 0; d < 32; d++) {
                float qd = q[d];
                zdot += qd * ksr[d];
                m0   += qd * kv0[d];
                m1   += qd * kv1[d];
            }
            float z = (float)SEQ / (zdot + 1e-6f);
            unsigned pack = (unsigned)f2bf(m0 * z) | ((unsigned)f2bf(m1 * z) << 16);
            *(unsigned*)(msg + (row + r2) * C + h * HD + vd) = pack;
        }
    }
}

extern "C" void kernel_launch(void* const* d_in, const int* in_sizes, int n_in,
                              void* d_out, int out_size, void* d_ws, size_t ws_size,
                              hipStream_t stream) {
    const float* x     = (const float*)d_in[0];
    const float* Wq    = (const float*)d_in[1];
    const float* Wk    = (const float*)d_in[2];
    const float* Wv    = (const float*)d_in[3];
    const float* Wm    = (const float*)d_in[4];
    const float* W1    = (const float*)d_in[5];
    const float* b1    = (const float*)d_in[6];
    const float* W2    = (const float*)d_in[7];
    const float* b2    = (const float*)d_in[8];
    const float* g_att = (const float*)d_in[9];
    const float* b_att = (const float*)d_in[10];
    const float* g_ffn = (const float*)d_in[11];
    const float* b_ffn = (const float*)d_in[12];
    float* out = (float*)d_out;

    // Workspace map (live ranges disjoint in time)
    char* ws = (char*)d_ws;
    u16*   Wqkvt = (u16*)(ws);                    // 1.5 MB
    u16*   Wmt   = (u16*)(ws + 0x180000);         // 0.5 MB
    u16*   W1t   = (u16*)(ws + 0x200000);         // 0.5 MB
    u16*   W2t   = (u16*)(ws + 0x280000);         // 0.5 MB
    float* KV    = (float*)(ws + 0x300000);       // 512 KB
    float* Ksum  = (float*)(ws + 0x380000);       // 16 KB
    u16*   hb    = (u16*)(ws + 0x400000);         // 32 MB (LN1 out; reused as msg)
    float* Pkv   = (float*)(ws + 0x400000);       // 16 MB, aliases hb (hb dead in step 4)
    float* PKsum = (float*)(ws + 0x1400000);      // 512 KB
    u16*   qkv   = (u16*)(ws + 0x2400000);        // 96 MB
    u16*   h2    = qkv;                           // 32 MB (qkv dead after step 5)
    u16*   f1    = (u16*)(ws + 0x4400000);        // 32 MB (in qkv tail, dead by step 8)

    // 1. weights -> bf16 transposed
    prep_weights<<<6 * 64, 256, 0, stream>>>(Wq, Wk, Wv, Wm, W1, W2,
                                             Wqkvt, Wmt, W1t, W2t);
    // 2. LN1
    ln_kernel<<<ROWS / 4, 256, 0, stream>>>(x, g_att, b_att, hb);
    // 3. qkv = h @ [Wq|Wk|Wv] with feature-map epilogue  (256^2 8-phase)
    gemm256<0><<<768, 512, 0, stream>>>(hb, Wqkvt, 1536, 6,
                                        qkv, nullptr, nullptr, nullptr);
    // 4. KV/Ksum: MFMA partials + final reduce (no atomics, no memset)
    kv_reduce<<<dim3(128, 8), 256, 0, stream>>>(qkv, Pkv, PKsum);
    kv_final<<<128, 256, 0, stream>>>(Pkv, PKsum, KV, Ksum);
    // 5. msg (overwrites hb region - Pkv already consumed)
    msg_kernel<<<1024, 256, 0, stream>>>(qkv, KV, Ksum, hb);
    // 6. x2 = x + msg @ Wm   (x2 lives in d_out)
    gemm256<1><<<256, 512, 0, stream>>>(hb, Wmt, 512, 2,
                                        nullptr, out, nullptr, x);
    // 7. LN2
    ln_kernel<<<ROWS / 4, 256, 0, stream>>>(out, g_ffn, b_ffn, h2);
    // 8. f1 = gelu(h2 @ W1 + b1)
    gemm256<2><<<256, 512, 0, stream>>>(h2, W1t, 512, 2,
                                        f1, nullptr, b1, nullptr);
    // 9. out = x2 + f1 @ W2 + b2   (in place on d_out)
    gemm256<3><<<256, 512, 0, stream>>>(f1, W2t, 512, 2,
                                        nullptr, out, b2, nullptr);
}

// Round 4
// 417.169 us; speedup vs baseline: 1.0142x; 1.0142x over previous
//
#include <hip/hip_runtime.h>
#include <hip/hip_bf16.h>
#include <math.h>

typedef unsigned short u16;
typedef __attribute__((ext_vector_type(8))) __bf16 bf16x8;
typedef __attribute__((ext_vector_type(4))) float floatx4;

#define SEQ   4096
#define BATCH 8
#define ROWS  32768   // BATCH*SEQ
#define C     512
#define NH    16
#define HD    32

__device__ inline u16 f2bf(float f) {
    union { float f; unsigned u; } v; v.f = f;
    unsigned r = (v.u + 0x7FFFu + ((v.u >> 16) & 1u)) >> 16;
    return (u16)r;
}
__device__ inline float bf2f(u16 h) {
    union { unsigned u; float f; } v; v.u = ((unsigned)h) << 16;
    return v.f;
}

// async global -> LDS, 16B per lane; lds ptr must be wave-uniform (HW adds lane*16)
__device__ inline void g2lds16(const u16* g, u16* l) {
    __builtin_amdgcn_global_load_lds((const __attribute__((address_space(1))) unsigned*)g,
                                     (__attribute__((address_space(3))) unsigned*)l, 16, 0, 0);
}

// generic LDS pointer -> 32-bit LDS byte offset (for inline-asm ds_read)
#define LDSA(p) ((unsigned)(size_t)(const __attribute__((address_space(3))) u16*)(p))

// ---------------- weight prep: fp32 (k,n) -> bf16 transposed (n,k), 64x64 LDS tiles ----------------
__global__ __launch_bounds__(256) void prep_weights(
    const float* __restrict__ Wq, const float* __restrict__ Wk,
    const float* __restrict__ Wv, const float* __restrict__ Wm,
    const float* __restrict__ W1, const float* __restrict__ W2,
    u16* __restrict__ Wqkvt, u16* __restrict__ Wmt,
    u16* __restrict__ W1t, u16* __restrict__ W2t)
{
    int blk = blockIdx.x;                 // 6 mats * 64 tiles
    int mat = blk >> 6;
    int tile = blk & 63;
    int k0 = (tile >> 3) * 64, n0 = (tile & 7) * 64;
    const float* src; u16* dst;
    switch (mat) {
        case 0: src = Wq; dst = Wqkvt;              break;
        case 1: src = Wk; dst = Wqkvt + 512*512;    break;
        case 2: src = Wv; dst = Wqkvt + 2*512*512;  break;
        case 3: src = Wm; dst = Wmt;                break;
        case 4: src = W1; dst = W1t;                break;
        default: src = W2; dst = W2t;               break;
    }
    __shared__ float ts[64][65];
    int t = threadIdx.x;
    #pragma unroll
    for (int i = 0; i < 16; i++) {
        int e = i * 256 + t;
        int kr = e >> 6, nc = e & 63;
        ts[kr][nc] = src[(size_t)(k0 + kr) * 512 + n0 + nc];   // coalesced 256B rows
    }
    __syncthreads();
    #pragma unroll
    for (int i = 0; i < 2; i++) {
        int e = i * 256 + t;                 // 512 chunks of 8
        int nr = e >> 3, kc0 = (e & 7) * 8;
        union { uint4 v; u16 u[8]; } o;
        #pragma unroll
        for (int q = 0; q < 8; q++) o.u[q] = f2bf(ts[kc0 + q][nr]);
        *(uint4*)(dst + (size_t)(n0 + nr) * 512 + k0 + kc0) = o.v;   // coalesced 16B stores
    }
}

// ---------------- layernorm: fp32 in -> bf16 out, one wave per row ----------------
__global__ __launch_bounds__(256) void ln_kernel(
    const float* __restrict__ in, const float* __restrict__ g,
    const float* __restrict__ b, u16* __restrict__ out)
{
    int row  = blockIdx.x * 4 + (threadIdx.x >> 6);
    int lane = threadIdx.x & 63;
    const float* p = in + (size_t)row * C + lane * 8;
    float4 v0 = *(const float4*)p;
    float4 v1 = *(const float4*)(p + 4);
    float s  = v0.x + v0.y + v0.z + v0.w + v1.x + v1.y + v1.z + v1.w;
    float s2 = v0.x*v0.x + v0.y*v0.y + v0.z*v0.z + v0.w*v0.w
             + v1.x*v1.x + v1.y*v1.y + v1.z*v1.z + v1.w*v1.w;
    #pragma unroll
    for (int off = 1; off < 64; off <<= 1) {
        s  += __shfl_xor(s, off);
        s2 += __shfl_xor(s2, off);
    }
    float mean = s * (1.f / C);
    float var  = s2 * (1.f / C) - mean * mean;
    float inv  = rsqrtf(var + 1e-6f);
    int c = lane * 8;
    float4 g0 = *(const float4*)(g + c), g1 = *(const float4*)(g + c + 4);
    float4 b0 = *(const float4*)(b + c), b1 = *(const float4*)(b + c + 4);
    union { uint4 v; u16 u[8]; } o;
    o.u[0] = f2bf((v0.x - mean) * inv * g0.x + b0.x);
    o.u[1] = f2bf((v0.y - mean) * inv * g0.y + b0.y);
    o.u[2] = f2bf((v0.z - mean) * inv * g0.z + b0.z);
    o.u[3] = f2bf((v0.w - mean) * inv * g0.w + b0.w);
    o.u[4] = f2bf((v1.x - mean) * inv * g1.x + b1.x);
    o.u[5] = f2bf((v1.y - mean) * inv * g1.y + b1.y);
    o.u[6] = f2bf((v1.z - mean) * inv * g1.z + b1.z);
    o.u[7] = f2bf((v1.w - mean) * inv * g1.w + b1.w);
    *(uint4*)(out + (size_t)row * C + c) = o.v;
}

// ---------------- bf16 MFMA GEMM, 256x256 tile, 8-phase counted-vmcnt schedule ----------------
// K fixed at 512. BM=BN=256, BK=64, 8 waves (2M x 4N), 512 threads, 128 KiB LDS.
// R2 fix (kept): 8 DISTINCT __shared__ arrays (precise DMA alias facts).
// R3 fix (kept): clobber-free waitcnt asm + sched_barrier(0) pins (rule #18).
// R4 fix: the per-phase LDS fragment reads are INLINE-ASM ds_read_b128. With compiler-visible
// ds_reads, SIInsertWaitcnts orders each read against in-flight global_load_lds at the loop
// merge point conservatively -> implicit near-drain per phase (measured ~2000cy/phase, 26%
// MfmaUtil in R2/R3 regardless of our manual waitcnts). Asm reads are invisible to that pass;
// ordering is carried entirely by the manual counted-vmcnt(4)+barrier protocol and the
// lgkmcnt(0)+sched_barrier(0) before the MFMA cluster.
// Stage schedule per iter (2 loads/wave each):
//   ph0: A1h1<-k+64   ph1: B1h0<-k+64   ph2: A0h0<-k+128  ph3: B0h1<-k+128 [vmcnt(4)]
//   ph4: A0h1<-k+128  ph5: B0h0<-k+128  ph6: A1h0<-k+192  ph7: B1h1<-k+192 [vmcnt(4)]
// vmcnt(4) leaves only the 4 newest loads (2 newest stage ops) outstanding; every slab-half
// read in the following 4 phases was staged >=2 stage-ops earlier -> landed. s_barrier after
// the vmcnt makes it cross-wave. Never drains to 0 in the main loop; tail peeled.

#define STG2(ARR, GBASE, KC)                                                    \
  do {                                                                          \
    const u16* _g = (GBASE) + (KC);                                             \
    u16* _l = (ARR) + w * 1024;                                                 \
    g2lds16(_g, _l);                                                            \
    g2lds16(_g + 8 * 512, _l + 512);                                            \
  } while (0)

// fragment loads via raw ds_read_b128 (invisible to SIInsertWaitcnts)
#define RDA(ARR)                                                                \
  do {                                                                          \
    unsigned _a0 = LDSA((ARR) + aoff + ck0);                                    \
    unsigned _a1 = LDSA((ARR) + aoff + ck1);                                    \
    asm volatile("ds_read_b128 %0, %1"             : "=v"(af0[0]) : "v"(_a0));  \
    asm volatile("ds_read_b128 %0, %1 offset:2048" : "=v"(af0[1]) : "v"(_a0));  \
    asm volatile("ds_read_b128 %0, %1 offset:4096" : "=v"(af0[2]) : "v"(_a0));  \
    asm volatile("ds_read_b128 %0, %1 offset:6144" : "=v"(af0[3]) : "v"(_a0));  \
    asm volatile("ds_read_b128 %0, %1"             : "=v"(af1[0]) : "v"(_a1));  \
    asm volatile("ds_read_b128 %0, %1 offset:2048" : "=v"(af1[1]) : "v"(_a1));  \
    asm volatile("ds_read_b128 %0, %1 offset:4096" : "=v"(af1[2]) : "v"(_a1));  \
    asm volatile("ds_read_b128 %0, %1 offset:6144" : "=v"(af1[3]) : "v"(_a1));  \
  } while (0)

#define RDB(ARR)                                                                \
  do {                                                                          \
    unsigned _b0 = LDSA((ARR) + boff + ck0);                                    \
    unsigned _b1 = LDSA((ARR) + boff + ck1);                                    \
    asm volatile("ds_read_b128 %0, %1"             : "=v"(bv0[0]) : "v"(_b0));  \
    asm volatile("ds_read_b128 %0, %1 offset:2048" : "=v"(bv0[1]) : "v"(_b0));  \
    asm volatile("ds_read_b128 %0, %1"             : "=v"(bv1[0]) : "v"(_b1));  \
    asm volatile("ds_read_b128 %0, %1 offset:2048" : "=v"(bv1[1]) : "v"(_b1));  \
  } while (0)

#define MFMA_(A, B, CC) __builtin_amdgcn_mfma_f32_16x16x32_bf16(                \
    __builtin_bit_cast(bf16x8, A), __builtin_bit_cast(bf16x8, B), CC, 0, 0, 0)

#define PHX(MH, NHI, STG, VM)                                                   \
  do {                                                                          \
    STG;                                                                        \
    __builtin_amdgcn_sched_barrier(0);                                          \
    if constexpr ((VM) == 4) asm volatile("s_waitcnt vmcnt(4)");                \
    else if constexpr ((VM) == 0) asm volatile("s_waitcnt vmcnt(0)");           \
    __builtin_amdgcn_s_barrier();                                               \
    asm volatile("s_waitcnt lgkmcnt(0)");                                       \
    __builtin_amdgcn_sched_barrier(0);                                          \
    __builtin_amdgcn_s_setprio(1);                                              \
    _Pragma("unroll") for (int ii = 0; ii < 4; ii++)                            \
      _Pragma("unroll") for (int jj = 0; jj < 2; jj++) {                        \
        acc[(MH)*4+ii][(NHI)*2+jj] = MFMA_(af0[ii], bv0[jj],                    \
                                           acc[(MH)*4+ii][(NHI)*2+jj]);         \
        acc[(MH)*4+ii][(NHI)*2+jj] = MFMA_(af1[ii], bv1[jj],                    \
                                           acc[(MH)*4+ii][(NHI)*2+jj]);         \
      }                                                                         \
    __builtin_amdgcn_s_setprio(0);                                              \
    __builtin_amdgcn_s_barrier();                                               \
    __builtin_amdgcn_sched_barrier(0);                                          \
  } while (0)

template <int EPI>
__global__ __launch_bounds__(512, 2) void gemm256(
    const u16* __restrict__ A, const u16* __restrict__ Bt,
    int ldc, int nx,
    u16* __restrict__ outb, float* __restrict__ outf,
    const float* __restrict__ bias, const float* __restrict__ resid)
{
    // 8 distinct LDS objects: [slab][half], each 128 rows x 64 cols bf16 = 16 KB
    __shared__ u16 A0h0[8192], A0h1[8192], A1h0[8192], A1h1[8192];
    __shared__ u16 B0h0[8192], B0h1[8192], B1h0[8192], B1h1[8192];

    const int t = threadIdx.x;
    const int w = t >> 6, l = t & 63, lr = l & 15, quad = l >> 4;
    const int wr = w >> 2, wc = w & 3;

    // grouped XCD swizzle: xcd g&7; within XCD sweep x-major over groups of 2 y-tiles
    const int g = blockIdx.x;
    const int xcd = g & 7;
    const int q = g >> 3;
    const int grp = q / (nx * 2), rem = q - grp * (nx * 2);
    const int tx = rem >> 1;
    const int ty = xcd * 16 + grp * 2 + (rem & 1);
    const int m0 = ty * 256, n0 = tx * 256;

    // staging addresses: wave w covers rows [w*16, w*16+16) of a 128-row half (2 loads)
    const int rh = w * 16 + (l >> 3);
    const int swz = (((l & 7) - (l >> 3)) & 7) * 8;   // rotated source chunk
    const u16* Ab0 = A  + (size_t)(m0 + rh) * 512 + swz;
    const u16* Bb0 = Bt + (size_t)(n0 + rh) * 512 + swz;
    const u16* Ab1 = Ab0 + (size_t)128 * 512;
    const u16* Bb1 = Bb0 + (size_t)128 * 512;

    // fragment read offsets (u16 units); row&7 == lr&7 -> physical chunk (m + lr)&7
    const int aoff = (wr * 64 + lr) * 64;
    const int boff = (wc * 32 + lr) * 64;
    const int ck0 = (((0 + quad + (lr & 7)) & 7) * 8);
    const int ck1 = (((4 + quad + (lr & 7)) & 7) * 8);

    floatx4 acc[8][4];
    #pragma unroll
    for (int i = 0; i < 8; i++)
        #pragma unroll
        for (int j = 0; j < 4; j++) { floatx4 z = {0.f, 0.f, 0.f, 0.f}; acc[i][j] = z; }

    floatx4 af0[4], af1[4], bv0[2], bv1[2];

    // prologue: slab0 <- tile0 (all 4 halves), slab1 <- tile1 {A-h0, B-h1}
    STG2(A0h0, Ab0, 0); STG2(A0h1, Ab1, 0); STG2(B0h0, Bb0, 0); STG2(B0h1, Bb1, 0);
    STG2(A1h0, Ab0, 64); STG2(B1h1, Bb1, 64);
    __builtin_amdgcn_sched_barrier(0);
    asm volatile("s_waitcnt vmcnt(4)");                // slab0's 8 landed
    __builtin_amdgcn_s_barrier();
    __builtin_amdgcn_sched_barrier(0);

    int kk = 0;
    for (int it = 0; it < 3; ++it, kk += 128) {        // K=512 -> 4 iters, last peeled
        RDA(A0h0); RDB(B0h0); PHX(0, 0, STG2(A1h1, Ab1, kk + 64),  -1);
        RDB(B0h1);            PHX(0, 1, STG2(B1h0, Bb0, kk + 64),  -1);
        RDA(A0h1);            PHX(1, 1, STG2(A0h0, Ab0, kk + 128), -1);
        RDB(B0h0);            PHX(1, 0, STG2(B0h1, Bb1, kk + 128),  4);
        RDA(A1h0); RDB(B1h0); PHX(0, 0, STG2(A0h1, Ab1, kk + 128), -1);
        RDB(B1h1);            PHX(0, 1, STG2(B0h0, Bb0, kk + 128), -1);
        RDA(A1h1);            PHX(1, 1, STG2(A1h0, Ab0, kk + 192), -1);
        RDB(B1h0);            PHX(1, 0, STG2(B1h1, Bb1, kk + 192),  4);
    }
    // tail (kk=384): slab0 holds 384; finish staging 448 into slab1; one vmcnt(0)
    RDA(A0h0); RDB(B0h0); PHX(0, 0, STG2(A1h1, Ab1, 448), -1);
    RDB(B0h1);            PHX(0, 1, STG2(B1h0, Bb0, 448), -1);
    RDA(A0h1);            PHX(1, 1, (void)0, -1);
    RDB(B0h0);            PHX(1, 0, (void)0,  0);
    RDA(A1h0); RDB(B1h0); PHX(0, 0, (void)0, -1);
    RDB(B1h1);            PHX(0, 1, (void)0, -1);
    RDA(A1h1);            PHX(1, 1, (void)0, -1);
    RDB(B1h0);            PHX(1, 0, (void)0, -1);

    // epilogue
    #pragma unroll
    for (int i = 0; i < 8; i++) {
        #pragma unroll
        for (int j = 0; j < 4; j++) {
            #pragma unroll
            for (int r = 0; r < 4; r++) {
                int row = m0 + (i >> 2) * 128 + wr * 64 + (i & 3) * 16 + quad * 4 + r;
                int col = n0 + (j >> 1) * 128 + wc * 32 + (j & 1) * 16 + lr;
                float v = acc[i][j][r];
                size_t idx = (size_t)row * ldc + col;
                if constexpr (EPI == 0) {
                    if (col < 1024) v = v > 0.f ? v + 1.f : __expf(v);
                    else            v *= (1.0f / SEQ);
                    outb[idx] = f2bf(v);
                } else if constexpr (EPI == 1) {
                    outf[idx] = resid[idx] + v;
                } else if constexpr (EPI == 2) {
                    v += bias[col];
                    v = 0.5f * v * (1.f + erff(v * 0.70710678118f));
                    outb[idx] = f2bf(v);
                } else {
                    outf[idx] = outf[idx] + v + bias[col];
                }
            }
        }
    }
}

// ---------------- KV partials via MFMA: per-wave private LDS tiles, no atomics ----------------
__global__ __launch_bounds__(256) void kv_reduce(
    const u16* __restrict__ qkv, float* __restrict__ Pkv, float* __restrict__ PKsum)
{
    const int bh = blockIdx.x;            // 0..127
    const int b = bh >> 4, h = bh & 15;
    const int chunk = blockIdx.y;         // 0..7
    const int t = threadIdx.x;
    const int w = t >> 6, l = t & 63, lr = l & 15, quad = l >> 4;
    __shared__ u16 lds[4 * 2 * 2048];     // [wave][buf][K 1024 | V 1024] = 32 KB

    const int sbase = chunk * 512 + w * 128;
    const u16* qbase = qkv + (size_t)b * SEQ * 1536 + 512 + h * HD;  // K part; V = +512

    const int sl0 = l >> 2;               // rows 0..15 (instr 0)
    const int sl1 = 16 + sl0;             // rows 16..31 (instr 1)
    const int cl  = l & 3;
    const int cg0 = (cl + (sl0 >> 3)) & 3;
    const int cg1 = (cl + (sl1 >> 3)) & 3;
    const int gof0 = sl0 * 1536 + cg0 * 8;
    const int gof1 = sl1 * 1536 + cg1 * 8;

    u16* myl = lds + w * 4096;

    const int offA0 = quad * 256 + ((((lr >> 3) + 0) - quad) & 3) * 8 + (lr & 7);  // d 0..15
    const int offA1 = quad * 256 + ((((lr >> 3) + 2) - quad) & 3) * 8 + (lr & 7);  // d 16..31

    floatx4 a00 = {0,0,0,0}, a01 = {0,0,0,0}, a10 = {0,0,0,0}, a11 = {0,0,0,0};
    float ks0 = 0.f, ks1 = 0.f;

    {
        const u16* gK = qbase + (size_t)sbase * 1536;
        g2lds16(gK + gof0,       myl);
        g2lds16(gK + gof1,       myl + 512);
        g2lds16(gK + 512 + gof0, myl + 1024);
        g2lds16(gK + 512 + gof1, myl + 1536);
    }
    #pragma unroll
    for (int st = 0; st < 4; st++) {
        if (st < 3) {                      // prefetch next buf before the drain
            const u16* gK = qbase + (size_t)(sbase + (st + 1) * 32) * 1536;
            u16* nl = myl + ((st + 1) & 1) * 2048;
            g2lds16(gK + gof0,       nl);
            g2lds16(gK + gof1,       nl + 512);
            g2lds16(gK + 512 + gof0, nl + 1024);
            g2lds16(gK + 512 + gof1, nl + 1536);
        }
        __syncthreads();                   // vmcnt(0) drain, compiler-safe fence
        const u16* lK = myl + (st & 1) * 2048;
        const u16* lV = lK + 1024;
        union { bf16x8 v; u16 u[8]; } fa0, fa1, fb0, fb1;
        #pragma unroll
        for (int j = 0; j < 8; j++) {
            fa0.u[j] = lK[offA0 + j * 32];
            fa1.u[j] = lK[offA1 + j * 32];
            fb0.u[j] = lV[offA0 + j * 32];
            fb1.u[j] = lV[offA1 + j * 32];
        }
        #pragma unroll
        for (int j = 0; j < 8; j++) { ks0 += bf2f(fa0.u[j]); ks1 += bf2f(fa1.u[j]); }
        a00 = __builtin_amdgcn_mfma_f32_16x16x32_bf16(fa0.v, fb0.v, a00, 0, 0, 0);
        a01 = __builtin_amdgcn_mfma_f32_16x16x32_bf16(fa0.v, fb1.v, a01, 0, 0, 0);
        a10 = __builtin_amdgcn_mfma_f32_16x16x32_bf16(fa1.v, fb0.v, a10, 0, 0, 0);
        a11 = __builtin_amdgcn_mfma_f32_16x16x32_bf16(fa1.v, fb1.v, a11, 0, 0, 0);
    }

    const int p = bh * 32 + chunk * 4 + w;
    float* dst = Pkv + (size_t)p * 1024;
    floatx4 accs[2][2] = {{a00, a01}, {a10, a11}};
    #pragma unroll
    for (int i = 0; i < 2; i++)
        #pragma unroll
        for (int j = 0; j < 2; j++)
            #pragma unroll
            for (int r = 0; r < 4; r++)
                dst[(i * 16 + quad * 4 + r) * 32 + j * 16 + lr] = accs[i][j][r];

    float k0 = ks0 + __shfl_xor(ks0, 16); k0 += __shfl_xor(k0, 32);
    float k1 = ks1 + __shfl_xor(ks1, 16); k1 += __shfl_xor(k1, 32);
    if (quad == 0) {
        PKsum[p * 32 + lr]      = k0;
        PKsum[p * 32 + 16 + lr] = k1;
    }
}

// ---------------- final reduce: KV[bh][1024] = sum of 32 partials; Ksum likewise ----------------
__global__ __launch_bounds__(256) void kv_final(
    const float* __restrict__ Pkv, const float* __restrict__ PKsum,
    float* __restrict__ KV, float* __restrict__ Ksum)
{
    const int bh = blockIdx.x;
    const int t = threadIdx.x;
    float a0 = 0.f, a1 = 0.f, a2 = 0.f, a3 = 0.f;
    for (int p = 0; p < 32; p++) {
        const float* src = Pkv + ((size_t)bh * 32 + p) * 1024;
        a0 += src[t];
        a1 += src[t + 256];
        a2 += src[t + 512];
        a3 += src[t + 768];
    }
    float* dst = KV + (size_t)bh * 1024;
    dst[t] = a0; dst[t + 256] = a1; dst[t + 512] = a2; dst[t + 768] = a3;
    if (t < 32) {
        float s = 0.f;
        for (int p = 0; p < 32; p++) s += PKsum[(bh * 32 + p) * 32 + t];
        Ksum[bh * 32 + t] = s;
    }
}

// ---------------- msg = (Q . KV) * SEQ / (Q . Ksum + eps) ----------------
__global__ __launch_bounds__(256) void msg_kernel(
    const u16* __restrict__ qkv, const float* __restrict__ KV,
    const float* __restrict__ Ksum, u16* __restrict__ msg)
{
    int blk = blockIdx.x;           // 1024 blocks
    int b = blk >> 7;
    int r0 = (blk & 127) * 32;
    int t = threadIdx.x;
    int h = t >> 4;
    int vd = (t & 15) * 2;
    float kv0[32], kv1[32], ksr[32];
    const float* kvh = KV + ((size_t)b * 16 + h) * 1024;
    const float* ksh = Ksum + (b * 16 + h) * 32;
    #pragma unroll
    for (int d = 0; d < 32; d++) {
        kv0[d] = kvh[d * 32 + vd];
        kv1[d] = kvh[d * 32 + vd + 1];
        ksr[d] = ksh[d];
    }
    __shared__ u16 Qs[4 * 512];
    const int srr = t >> 6;
    const int scc = (t & 63) * 8;
    for (int rg = 0; rg < 32; rg += 4) {
        size_t row = (size_t)b * SEQ + r0 + rg;
        uint4 qv = *(const uint4*)(qkv + (row + srr) * 1536 + scc);
        __syncthreads();
        *(uint4*)(Qs + srr * 512 + scc) = qv;
        __syncthreads();
        #pragma unroll
        for (int r2 = 0; r2 < 4; r2++) {
            const u16* qp = Qs + r2 * 512 + h * HD;
            float q[32];
            #pragma unroll
            for (int i0 = 0; i0 < 32; i0 += 8) {
                union { uint4 v; u16 u[8]; } uu;
                uu.v = *(const uint4*)(qp + i0);
                #pragma unroll
                for (int jq = 0; jq < 8; jq++) q[i0 + jq] = bf2f(uu.u[jq]);
            }
            float zdot = 0.f, m0 = 0.f, m1 = 0.f;
            #pragma unroll
            for (int d = 0; d < 32; d++) {
                float qd = q[d];
                zdot += qd * ksr[d];
                m0   += qd * kv0[d];
                m1   += qd * kv1[d];
            }
            float z = (float)SEQ / (zdot + 1e-6f);
            unsigned pack = (unsigned)f2bf(m0 * z) | ((unsigned)f2bf(m1 * z) << 16);
            *(unsigned*)(msg + (row + r2) * C + h * HD + vd) = pack;
        }
    }
}

extern "C" void kernel_launch(void* const* d_in, const int* in_sizes, int n_in,
                              void* d_out, int out_size, void* d_ws, size_t ws_size,
                              hipStream_t stream) {
    const float* x     = (const float*)d_in[0];
    const float* Wq    = (const float*)d_in[1];
    const float* Wk    = (const float*)d_in[2];
    const float* Wv    = (const float*)d_in[3];
    const float* Wm    = (const float*)d_in[4];
    const float* W1    = (const float*)d_in[5];
    const float* b1    = (const float*)d_in[6];
    const float* W2    = (const float*)d_in[7];
    const float* b2    = (const float*)d_in[8];
    const float* g_att = (const float*)d_in[9];
    const float* b_att = (const float*)d_in[10];
    const float* g_ffn = (const float*)d_in[11];
    const float* b_ffn = (const float*)d_in[12];
    float* out = (float*)d_out;

    // Workspace map (live ranges disjoint in time)
    char* ws = (char*)d_ws;
    u16*   Wqkvt = (u16*)(ws);                    // 1.5 MB
    u16*   Wmt   = (u16*)(ws + 0x180000);         // 0.5 MB
    u16*   W1t   = (u16*)(ws + 0x200000);         // 0.5 MB
    u16*   W2t   = (u16*)(ws + 0x280000);         // 0.5 MB
    float* KV    = (float*)(ws + 0x300000);       // 512 KB
    float* Ksum  = (float*)(ws + 0x380000);       // 16 KB
    u16*   hb    = (u16*)(ws + 0x400000);         // 32 MB (LN1 out; reused as msg)
    float* Pkv   = (float*)(ws + 0x400000);       // 16 MB, aliases hb (hb dead in step 4)
    float* PKsum = (float*)(ws + 0x1400000);      // 512 KB
    u16*   qkv   = (u16*)(ws + 0x2400000);        // 96 MB
    u16*   h2    = qkv;                           // 32 MB (qkv dead after step 5)
    u16*   f1    = (u16*)(ws + 0x4400000);        // 32 MB (in qkv tail, dead by step 8)

    // 1. weights -> bf16 transposed
    prep_weights<<<6 * 64, 256, 0, stream>>>(Wq, Wk, Wv, Wm, W1, W2,
                                             Wqkvt, Wmt, W1t, W2t);
    // 2. LN1
    ln_kernel<<<ROWS / 4, 256, 0, stream>>>(x, g_att, b_att, hb);
    // 3. qkv = h @ [Wq|Wk|Wv] with feature-map epilogue  (256^2 8-phase)
    gemm256<0><<<768, 512, 0, stream>>>(hb, Wqkvt, 1536, 6,
                                        qkv, nullptr, nullptr, nullptr);
    // 4. KV/Ksum: MFMA partials + final reduce (no atomics, no memset)
    kv_reduce<<<dim3(128, 8), 256, 0, stream>>>(qkv, Pkv, PKsum);
    kv_final<<<128, 256, 0, stream>>>(Pkv, PKsum, KV, Ksum);
    // 5. msg (overwrites hb region - Pkv already consumed)
    msg_kernel<<<1024, 256, 0, stream>>>(qkv, KV, Ksum, hb);
    // 6. x2 = x + msg @ Wm   (x2 lives in d_out)
    gemm256<1><<<256, 512, 0, stream>>>(hb, Wmt, 512, 2,
                                        nullptr, out, nullptr, x);
    // 7. LN2
    ln_kernel<<<ROWS / 4, 256, 0, stream>>>(out, g_ffn, b_ffn, h2);
    // 8. f1 = gelu(h2 @ W1 + b1)
    gemm256<2><<<256, 512, 0, stream>>>(h2, W1t, 512, 2,
                                        f1, nullptr, b1, nullptr);
    // 9. out = x2 + f1 @ W2 + b2   (in place on d_out)
    gemm256<3><<<256, 512, 0, stream>>>(f1, W2t, 512, 2,
                                        nullptr, out, b2, nullptr);
}

// Round 5
// 392.434 us; speedup vs baseline: 1.0781x; 1.0630x over previous
//
#include <hip/hip_runtime.h>
#include <hip/hip_bf16.h>
#include <math.h>

typedef unsigned short u16;
typedef __attribute__((ext_vector_type(8))) __bf16 bf16x8;
typedef __attribute__((ext_vector_type(4))) float floatx4;

#define SEQ   4096
#define BATCH 8
#define ROWS  32768   // BATCH*SEQ
#define C     512
#define NH    16
#define HD    32

__device__ inline u16 f2bf(float f) {
    union { float f; unsigned u; } v; v.f = f;
    unsigned r = (v.u + 0x7FFFu + ((v.u >> 16) & 1u)) >> 16;
    return (u16)r;
}
__device__ inline float bf2f(u16 h) {
    union { unsigned u; float f; } v; v.u = ((unsigned)h) << 16;
    return v.f;
}

// async global -> LDS, 16B per lane; lds ptr must be wave-uniform (HW adds lane*16)
__device__ inline void g2lds16(const u16* g, u16* l) {
    __builtin_amdgcn_global_load_lds((const __attribute__((address_space(1))) unsigned*)g,
                                     (__attribute__((address_space(3))) unsigned*)l, 16, 0, 0);
}

// generic LDS pointer -> 32-bit LDS byte offset (for inline-asm ds_read)
#define LDSA(p) ((unsigned)(size_t)(const __attribute__((address_space(3))) u16*)(p))

// ---------------- weight prep: fp32 (k,n) -> bf16 transposed (n,k), 64x64 LDS tiles ----------------
__global__ __launch_bounds__(256) void prep_weights(
    const float* __restrict__ Wq, const float* __restrict__ Wk,
    const float* __restrict__ Wv, const float* __restrict__ Wm,
    const float* __restrict__ W1, const float* __restrict__ W2,
    u16* __restrict__ Wqkvt, u16* __restrict__ Wmt,
    u16* __restrict__ W1t, u16* __restrict__ W2t)
{
    int blk = blockIdx.x;                 // 6 mats * 64 tiles
    int mat = blk >> 6;
    int tile = blk & 63;
    int k0 = (tile >> 3) * 64, n0 = (tile & 7) * 64;
    const float* src; u16* dst;
    switch (mat) {
        case 0: src = Wq; dst = Wqkvt;              break;
        case 1: src = Wk; dst = Wqkvt + 512*512;    break;
        case 2: src = Wv; dst = Wqkvt + 2*512*512;  break;
        case 3: src = Wm; dst = Wmt;                break;
        case 4: src = W1; dst = W1t;                break;
        default: src = W2; dst = W2t;               break;
    }
    __shared__ float ts[64][65];
    int t = threadIdx.x;
    #pragma unroll
    for (int i = 0; i < 16; i++) {
        int e = i * 256 + t;
        int kr = e >> 6, nc = e & 63;
        ts[kr][nc] = src[(size_t)(k0 + kr) * 512 + n0 + nc];   // coalesced 256B rows
    }
    __syncthreads();
    #pragma unroll
    for (int i = 0; i < 2; i++) {
        int e = i * 256 + t;                 // 512 chunks of 8
        int nr = e >> 3, kc0 = (e & 7) * 8;
        union { uint4 v; u16 u[8]; } o;
        #pragma unroll
        for (int q = 0; q < 8; q++) o.u[q] = f2bf(ts[kc0 + q][nr]);
        *(uint4*)(dst + (size_t)(n0 + nr) * 512 + k0 + kc0) = o.v;   // coalesced 16B stores
    }
}

// ---------------- layernorm: fp32 in -> bf16 out, one wave per row ----------------
__global__ __launch_bounds__(256) void ln_kernel(
    const float* __restrict__ in, const float* __restrict__ g,
    const float* __restrict__ b, u16* __restrict__ out)
{
    int row  = blockIdx.x * 4 + (threadIdx.x >> 6);
    int lane = threadIdx.x & 63;
    const float* p = in + (size_t)row * C + lane * 8;
    float4 v0 = *(const float4*)p;
    float4 v1 = *(const float4*)(p + 4);
    float s  = v0.x + v0.y + v0.z + v0.w + v1.x + v1.y + v1.z + v1.w;
    float s2 = v0.x*v0.x + v0.y*v0.y + v0.z*v0.z + v0.w*v0.w
             + v1.x*v1.x + v1.y*v1.y + v1.z*v1.z + v1.w*v1.w;
    #pragma unroll
    for (int off = 1; off < 64; off <<= 1) {
        s  += __shfl_xor(s, off);
        s2 += __shfl_xor(s2, off);
    }
    float mean = s * (1.f / C);
    float var  = s2 * (1.f / C) - mean * mean;
    float inv  = rsqrtf(var + 1e-6f);
    int c = lane * 8;
    float4 g0 = *(const float4*)(g + c), g1 = *(const float4*)(g + c + 4);
    float4 b0 = *(const float4*)(b + c), b1 = *(const float4*)(b + c + 4);
    union { uint4 v; u16 u[8]; } o;
    o.u[0] = f2bf((v0.x - mean) * inv * g0.x + b0.x);
    o.u[1] = f2bf((v0.y - mean) * inv * g0.y + b0.y);
    o.u[2] = f2bf((v0.z - mean) * inv * g0.z + b0.z);
    o.u[3] = f2bf((v0.w - mean) * inv * g0.w + b0.w);
    o.u[4] = f2bf((v1.x - mean) * inv * g1.x + b1.x);
    o.u[5] = f2bf((v1.y - mean) * inv * g1.y + b1.y);
    o.u[6] = f2bf((v1.z - mean) * inv * g1.z + b1.z);
    o.u[7] = f2bf((v1.w - mean) * inv * g1.w + b1.w);
    *(uint4*)(out + (size_t)row * C + c) = o.v;
}

// ================= gemm_stream: barrier-free per-wave pipelined GEMM (qkv) ==================
// Structure: block = 512 thr = 8 waves; per block 256 rows x 64 cols; K=512 in 8 steps.
// LDS 128KB: Bs[64 n-rows][512 K] (64KB, whole panel resident) + per-wave A dbuf 2x[32][64].
// ONE s_barrier total (after B staged). Per-wave counted vmcnt(4) protects only the wave's
// OWN A-loads (wave computes exactly the rows it stages). Asm ds_reads (invisible to
// SIInsertWaitcnts). No lockstep: a stalled wave never blocks the other 7.
// B LDS layout: row r at r*512 u16; 16B chunk rotation within each 128B sub-block
// (phys&7 = (logical + r)&7) -- same bank pattern as gemm_tile's A (measured 0 conflicts).
// A layout/rotation identical to proven gemm_tile staging.

#define DSR(D, AR, OFFS) \
    asm volatile("ds_read_b128 %0, %1 offset:" OFFS : "=v"(D) : "v"(AR))

#define MFMA_(A, B, CC) __builtin_amdgcn_mfma_f32_16x16x32_bf16(                \
    __builtin_bit_cast(bf16x8, A), __builtin_bit_cast(bf16x8, B), CC, 0, 0, 0)

#define STGA_S(BUF, KK)                                                         \
  do {                                                                          \
    g2lds16(Ag + 0 * 4096 + (KK), Ald + (BUF) * 2048 + 0 * 512);                \
    g2lds16(Ag + 1 * 4096 + (KK), Ald + (BUF) * 2048 + 1 * 512);                \
    g2lds16(Ag + 2 * 4096 + (KK), Ald + (BUF) * 2048 + 2 * 512);                \
    g2lds16(Ag + 3 * 4096 + (KK), Ald + (BUF) * 2048 + 3 * 512);                \
  } while (0)

#define GITER(VM, AO0, AO1, DODMA, BUF, KKN)                                    \
  do {                                                                          \
    asm volatile("s_waitcnt vmcnt(" VM ")");                                    \
    __builtin_amdgcn_sched_barrier(0);                                          \
    DSR(a00, vA0, AO0); DSR(a10, vA0, AO1);                                     \
    DSR(a01, vA1, AO0); DSR(a11, vA1, AO1);                                     \
    DSR(b00, vB0, "0");     DSR(b10, vB0, "16384");                             \
    DSR(b20, vB0, "32768"); DSR(b30, vB0, "49152");                             \
    DSR(b01, vB1, "0");     DSR(b11, vB1, "16384");                             \
    DSR(b21, vB1, "32768"); DSR(b31, vB1, "49152");                             \
    vB0 += 128; vB1 += 128;                                                     \
    asm volatile("s_waitcnt lgkmcnt(0)");                                       \
    __builtin_amdgcn_sched_barrier(0);                                          \
    if (DODMA) { STGA_S(BUF, KKN); }                                            \
    __builtin_amdgcn_sched_barrier(0);                                          \
    __builtin_amdgcn_s_setprio(1);                                              \
    acc[0][0] = MFMA_(a00, b00, acc[0][0]);                                     \
    acc[0][1] = MFMA_(a00, b10, acc[0][1]);                                     \
    acc[0][2] = MFMA_(a00, b20, acc[0][2]);                                     \
    acc[0][3] = MFMA_(a00, b30, acc[0][3]);                                     \
    acc[1][0] = MFMA_(a10, b00, acc[1][0]);                                     \
    acc[1][1] = MFMA_(a10, b10, acc[1][1]);                                     \
    acc[1][2] = MFMA_(a10, b20, acc[1][2]);                                     \
    acc[1][3] = MFMA_(a10, b30, acc[1][3]);                                     \
    acc[0][0] = MFMA_(a01, b01, acc[0][0]);                                     \
    acc[0][1] = MFMA_(a01, b11, acc[0][1]);                                     \
    acc[0][2] = MFMA_(a01, b21, acc[0][2]);                                     \
    acc[0][3] = MFMA_(a01, b31, acc[0][3]);                                     \
    acc[1][0] = MFMA_(a11, b01, acc[1][0]);                                     \
    acc[1][1] = MFMA_(a11, b11, acc[1][1]);                                     \
    acc[1][2] = MFMA_(a11, b21, acc[1][2]);                                     \
    acc[1][3] = MFMA_(a11, b31, acc[1][3]);                                     \
    __builtin_amdgcn_s_setprio(0);                                              \
  } while (0)

template <int EPI>
__global__ __launch_bounds__(512, 2) void gemm_stream(
    const u16* __restrict__ A, const u16* __restrict__ Bt,
    int ldc, int nx,
    u16* __restrict__ outb, float* __restrict__ outf,
    const float* __restrict__ bias, const float* __restrict__ resid)
{
    __shared__ u16 LSD[65536];   // [0,32768): Bs[64][512]; [32768,65536): 8 waves x 2x[32][64]
    const int t = threadIdx.x;
    const int w = t >> 6, l = t & 63, lr = l & 15, quad = l >> 4;

    // grouped XCD swizzle: 2 y-tiles per group, x-major inside (A group + B panel L2-hot)
    const int g = blockIdx.x;
    const int xcd = g & 7;
    const int q = g >> 3;
    const int npg = nx * 2;
    const int grp = q / npg, rem = q - grp * npg;
    const int tx = rem >> 1;
    const int ty = xcd * 16 + grp * 2 + (rem & 1);
    const int wm0 = ty * 256 + w * 32;      // this wave's first output row
    const int n0  = tx * 64;

    // ---- B staging: wave w stages rows w*8..w*8+7 of the 64-row panel.
    // LDS[r][phys chunk p] = Bt[n0+r][logical (p&~7)|((p-r)&7)]; lane l covers phys p=l.
    const int brow = w * 8;
    #pragma unroll
    for (int j = 0; j < 8; j++) {
        int r = brow + j;
        const u16* src = Bt + (size_t)(n0 + r) * 512 + (((l & 56) | ((l - r) & 7)) * 8);
        g2lds16(src, (u16*)&LSD[r * 512]);
    }

    // ---- A staging (proven gemm_tile rotation): lane l -> row l>>3, phys chunk l&7
    const int arow = l >> 3;
    const int aswz = (((l & 7) - arow) & 7) * 8;
    const u16* Ag = A + (size_t)(wm0 + arow) * 512 + aswz;
    u16* Ald = (u16*)&LSD[32768 + w * 4096];

    STGA_S(0, 0);       // buf0 <- k=0
    STGA_S(1, 64);      // buf1 <- k=64
    __builtin_amdgcn_sched_barrier(0);
    asm volatile("s_waitcnt vmcnt(8)");      // own 8 B-writes landed (8 A still in flight)
    __builtin_amdgcn_s_barrier();            // => ALL waves' B landed; A untouched
    __builtin_amdgcn_sched_barrier(0);

    // fragment read addresses (bytes in LDS)
    const int ck0 = ((0 + quad + (lr & 7)) & 7) * 8;   // u16 units
    const int ck1 = ((4 + quad + (lr & 7)) & 7) * 8;
    unsigned vB0 = LDSA(LSD + lr * 512 + ck0);                         // + nf*16384 + kt*128
    unsigned vB1 = LDSA(LSD + lr * 512 + ck1);
    unsigned vA0 = LDSA(LSD + 32768 + w * 4096 + lr * 64 + ck0);       // + i*2048 + buf*4096
    unsigned vA1 = LDSA(LSD + 32768 + w * 4096 + lr * 64 + ck1);

    floatx4 acc[2][4];
    #pragma unroll
    for (int i = 0; i < 2; i++)
        #pragma unroll
        for (int j = 0; j < 4; j++) { floatx4 z = {0.f, 0.f, 0.f, 0.f}; acc[i][j] = z; }
    floatx4 a00, a01, a10, a11, b00, b10, b20, b30, b01, b11, b21, b31;

    // K loop, fully unrolled: kt -> buf kt&1; prefetch kt+2 into same buf
    GITER("4", "0",    "2048", 1, 0, 128);
    GITER("4", "4096", "6144", 1, 1, 192);
    GITER("4", "0",    "2048", 1, 0, 256);
    GITER("4", "4096", "6144", 1, 1, 320);
    GITER("4", "0",    "2048", 1, 0, 384);
    GITER("4", "4096", "6144", 1, 1, 448);
    GITER("4", "0",    "2048", 0, 0, 0);
    GITER("0", "4096", "6144", 0, 1, 0);

    // epilogue
    #pragma unroll
    for (int i = 0; i < 2; i++) {
        #pragma unroll
        for (int nf = 0; nf < 4; nf++) {
            #pragma unroll
            for (int r = 0; r < 4; r++) {
                int row = wm0 + i * 16 + quad * 4 + r;
                int col = n0 + nf * 16 + lr;
                float v = acc[i][nf][r];
                size_t idx = (size_t)row * ldc + col;
                if constexpr (EPI == 0) {
                    if (col < 1024) v = v > 0.f ? v + 1.f : __expf(v);
                    else            v *= (1.0f / SEQ);
                    outb[idx] = f2bf(v);
                } else if constexpr (EPI == 1) {
                    outf[idx] = resid[idx] + v;
                } else if constexpr (EPI == 2) {
                    v += bias[col];
                    v = 0.5f * v * (1.f + erff(v * 0.70710678118f));
                    outb[idx] = f2bf(v);
                } else {
                    outf[idx] = outf[idx] + v + bias[col];
                }
            }
        }
    }
}

// ---------------- bf16 MFMA GEMM, 128x128 tile (R0 proven structure, grouped swizzle) ------------
template <int EPI>
__global__ __launch_bounds__(256, 2) void gemm_tile(
    const u16* __restrict__ A, const u16* __restrict__ Bt,
    int K, int ldc, int nx,
    u16* __restrict__ outb, float* __restrict__ outf,
    const float* __restrict__ bias, const float* __restrict__ resid)
{
    __shared__ u16 lsA[128 * 64];
    __shared__ u16 lsB[128 * 64];
    const int t = threadIdx.x;
    const int w = t >> 6, l = t & 63, lr = l & 15, quad = l >> 4;
    // grouped XCD swizzle: 2 y-tiles per group, x-major inside the group
    const int g = blockIdx.x;
    const int xcd = g & 7;
    const int q = g >> 3;
    const int npg = nx * 2;
    const int grp = q / npg, rem = q - grp * npg;
    const int tx = rem >> 1;
    const int ty = xcd * 32 + grp * 2 + (rem & 1);
    const int m0 = ty * 128, n0 = tx * 128;
    const int RW = (w >> 1) * 64, CW = (w & 1) * 64;

    floatx4 acc[4][4];
    #pragma unroll
    for (int i = 0; i < 4; i++)
        #pragma unroll
        for (int j = 0; j < 4; j++) { floatx4 z = {0.f, 0.f, 0.f, 0.f}; acc[i][j] = z; }

    const int srow = w * 32 + (l >> 3);
    const int scol = (((l & 7) - (l >> 3)) & 7) * 8;      // row&7 == l>>3 here
    const u16* Ag = A  + (size_t)(m0 + srow) * K + scol;
    const u16* Bg = Bt + (size_t)(n0 + srow) * K + scol;
    u16* lAw = lsA + w * 2048;
    u16* lBw = lsB + w * 2048;

    for (int kk = 0; kk < K; kk += 64) {
        __syncthreads();
        #pragma unroll
        for (int c = 0; c < 4; c++) {
            g2lds16(Ag + (size_t)(c * 8) * K + kk, lAw + c * 512);
            g2lds16(Bg + (size_t)(c * 8) * K + kk, lBw + c * 512);
        }
        __syncthreads();
        #pragma unroll
        for (int ks = 0; ks < 2; ks++) {
            bf16x8 af[4], bfr[4];
            const int m = ((ks * 4 + quad + (lr & 7)) & 7) * 8;
            #pragma unroll
            for (int i = 0; i < 4; i++) {
                af[i]  = *(const bf16x8*)(lsA + (RW + i * 16 + lr) * 64 + m);
                bfr[i] = *(const bf16x8*)(lsB + (CW + i * 16 + lr) * 64 + m);
            }
            #pragma unroll
            for (int i = 0; i < 4; i++)
                #pragma unroll
                for (int j = 0; j < 4; j++)
                    acc[i][j] = __builtin_amdgcn_mfma_f32_16x16x32_bf16(af[i], bfr[j], acc[i][j], 0, 0, 0);
        }
    }

    #pragma unroll
    for (int i = 0; i < 4; i++) {
        #pragma unroll
        for (int j = 0; j < 4; j++) {
            #pragma unroll
            for (int r = 0; r < 4; r++) {
                int row = m0 + RW + i * 16 + quad * 4 + r;
                int col = n0 + CW + j * 16 + lr;
                float v = acc[i][j][r];
                size_t idx = (size_t)row * ldc + col;
                if constexpr (EPI == 0) {
                    if (col < 1024) v = v > 0.f ? v + 1.f : __expf(v);
                    else            v *= (1.0f / SEQ);
                    outb[idx] = f2bf(v);
                } else if constexpr (EPI == 1) {
                    outf[idx] = resid[idx] + v;
                } else if constexpr (EPI == 2) {
                    v += bias[col];
                    v = 0.5f * v * (1.f + erff(v * 0.70710678118f));
                    outb[idx] = f2bf(v);
                } else {
                    outf[idx] = outf[idx] + v + bias[col];
                }
            }
        }
    }
}

// ---------------- KV partials via MFMA: per-wave private LDS tiles, no atomics ----------------
__global__ __launch_bounds__(256) void kv_reduce(
    const u16* __restrict__ qkv, float* __restrict__ Pkv, float* __restrict__ PKsum)
{
    const int bh = blockIdx.x;            // 0..127
    const int b = bh >> 4, h = bh & 15;
    const int chunk = blockIdx.y;         // 0..7
    const int t = threadIdx.x;
    const int w = t >> 6, l = t & 63, lr = l & 15, quad = l >> 4;
    __shared__ u16 lds[4 * 2 * 2048];     // [wave][buf][K 1024 | V 1024] = 32 KB

    const int sbase = chunk * 512 + w * 128;
    const u16* qbase = qkv + (size_t)b * SEQ * 1536 + 512 + h * HD;  // K part; V = +512

    const int sl0 = l >> 2;               // rows 0..15 (instr 0)
    const int sl1 = 16 + sl0;             // rows 16..31 (instr 1)
    const int cl  = l & 3;
    const int cg0 = (cl + (sl0 >> 3)) & 3;
    const int cg1 = (cl + (sl1 >> 3)) & 3;
    const int gof0 = sl0 * 1536 + cg0 * 8;
    const int gof1 = sl1 * 1536 + cg1 * 8;

    u16* myl = lds + w * 4096;

    const int offA0 = quad * 256 + ((((lr >> 3) + 0) - quad) & 3) * 8 + (lr & 7);  // d 0..15
    const int offA1 = quad * 256 + ((((lr >> 3) + 2) - quad) & 3) * 8 + (lr & 7);  // d 16..31

    floatx4 a00 = {0,0,0,0}, a01 = {0,0,0,0}, a10 = {0,0,0,0}, a11 = {0,0,0,0};
    float ks0 = 0.f, ks1 = 0.f;

    {
        const u16* gK = qbase + (size_t)sbase * 1536;
        g2lds16(gK + gof0,       myl);
        g2lds16(gK + gof1,       myl + 512);
        g2lds16(gK + 512 + gof0, myl + 1024);
        g2lds16(gK + 512 + gof1, myl + 1536);
    }
    #pragma unroll
    for (int st = 0; st < 4; st++) {
        if (st < 3) {                      // prefetch next buf before the drain
            const u16* gK = qbase + (size_t)(sbase + (st + 1) * 32) * 1536;
            u16* nl = myl + ((st + 1) & 1) * 2048;
            g2lds16(gK + gof0,       nl);
            g2lds16(gK + gof1,       nl + 512);
            g2lds16(gK + 512 + gof0, nl + 1024);
            g2lds16(gK + 512 + gof1, nl + 1536);
        }
        __syncthreads();                   // vmcnt(0) drain, compiler-safe fence
        const u16* lK = myl + (st & 1) * 2048;
        const u16* lV = lK + 1024;
        union { bf16x8 v; u16 u[8]; } fa0, fa1, fb0, fb1;
        #pragma unroll
        for (int j = 0; j < 8; j++) {
            fa0.u[j] = lK[offA0 + j * 32];
            fa1.u[j] = lK[offA1 + j * 32];
            fb0.u[j] = lV[offA0 + j * 32];
            fb1.u[j] = lV[offA1 + j * 32];
        }
        #pragma unroll
        for (int j = 0; j < 8; j++) { ks0 += bf2f(fa0.u[j]); ks1 += bf2f(fa1.u[j]); }
        a00 = __builtin_amdgcn_mfma_f32_16x16x32_bf16(fa0.v, fb0.v, a00, 0, 0, 0);
        a01 = __builtin_amdgcn_mfma_f32_16x16x32_bf16(fa0.v, fb1.v, a01, 0, 0, 0);
        a10 = __builtin_amdgcn_mfma_f32_16x16x32_bf16(fa1.v, fb0.v, a10, 0, 0, 0);
        a11 = __builtin_amdgcn_mfma_f32_16x16x32_bf16(fa1.v, fb1.v, a11, 0, 0, 0);
    }

    const int p = bh * 32 + chunk * 4 + w;
    float* dst = Pkv + (size_t)p * 1024;
    floatx4 accs[2][2] = {{a00, a01}, {a10, a11}};
    #pragma unroll
    for (int i = 0; i < 2; i++)
        #pragma unroll
        for (int j = 0; j < 2; j++)
            #pragma unroll
            for (int r = 0; r < 4; r++)
                dst[(i * 16 + quad * 4 + r) * 32 + j * 16 + lr] = accs[i][j][r];

    float k0 = ks0 + __shfl_xor(ks0, 16); k0 += __shfl_xor(k0, 32);
    float k1 = ks1 + __shfl_xor(ks1, 16); k1 += __shfl_xor(k1, 32);
    if (quad == 0) {
        PKsum[p * 32 + lr]      = k0;
        PKsum[p * 32 + 16 + lr] = k1;
    }
}

// ---------------- final reduce: widened to 512 blocks (was 128 -> half the GPU idle) ----------
__global__ __launch_bounds__(256) void kv_final(
    const float* __restrict__ Pkv, const float* __restrict__ PKsum,
    float* __restrict__ KV, float* __restrict__ Ksum)
{
    const int blk = blockIdx.x;          // 512 = 128 bh x 4 parts
    const int bh = blk >> 2, part = blk & 3;
    const int t = threadIdx.x;
    const float* src = Pkv + (size_t)bh * 32 * 1024 + part * 256 + t;
    float a = 0.f;
    #pragma unroll 4
    for (int p = 0; p < 32; p++) a += src[(size_t)p * 1024];
    KV[(size_t)bh * 1024 + part * 256 + t] = a;
    if (part == 0 && t < 32) {
        float s = 0.f;
        for (int p = 0; p < 32; p++) s += PKsum[(bh * 32 + p) * 32 + t];
        Ksum[bh * 32 + t] = s;
    }
}

// ---------------- msg = (Q . KV) * SEQ / (Q . Ksum + eps) ----------------
__global__ __launch_bounds__(256) void msg_kernel(
    const u16* __restrict__ qkv, const float* __restrict__ KV,
    const float* __restrict__ Ksum, u16* __restrict__ msg)
{
    int blk = blockIdx.x;           // 1024 blocks
    int b = blk >> 7;
    int r0 = (blk & 127) * 32;
    int t = threadIdx.x;
    int h = t >> 4;
    int vd = (t & 15) * 2;
    float kv0[32], kv1[32], ksr[32];
    const float* kvh = KV + ((size_t)b * 16 + h) * 1024;
    const float* ksh = Ksum + (b * 16 + h) * 32;
    #pragma unroll
    for (int d = 0; d < 32; d++) {
        kv0[d] = kvh[d * 32 + vd];
        kv1[d] = kvh[d * 32 + vd + 1];
        ksr[d] = ksh[d];
    }
    __shared__ u16 Qs[4 * 512];
    const int srr = t >> 6;
    const int scc = (t & 63) * 8;
    for (int rg = 0; rg < 32; rg += 4) {
        size_t row = (size_t)b * SEQ + r0 + rg;
        uint4 qv = *(const uint4*)(qkv + (row + srr) * 1536 + scc);
        __syncthreads();
        *(uint4*)(Qs + srr * 512 + scc) = qv;
        __syncthreads();
        #pragma unroll
        for (int r2 = 0; r2 < 4; r2++) {
            const u16* qp = Qs + r2 * 512 + h * HD;
            float q[32];
            #pragma unroll
            for (int i0 = 0; i0 < 32; i0 += 8) {
                union { uint4 v; u16 u[8]; } uu;
                uu.v = *(const uint4*)(qp + i0);
                #pragma unroll
                for (int jq = 0; jq < 8; jq++) q[i0 + jq] = bf2f(uu.u[jq]);
            }
            float zdot = 0.f, m0 = 0.f, m1 = 0.f;
            #pragma unroll
            for (int d = 0; d < 32; d++) {
                float qd = q[d];
                zdot += qd * ksr[d];
                m0   += qd * kv0[d];
                m1   += qd * kv1[d];
            }
            float z = (float)SEQ / (zdot + 1e-6f);
            unsigned pack = (unsigned)f2bf(m0 * z) | ((unsigned)f2bf(m1 * z) << 16);
            *(unsigned*)(msg + (row + r2) * C + h * HD + vd) = pack;
        }
    }
}

extern "C" void kernel_launch(void* const* d_in, const int* in_sizes, int n_in,
                              void* d_out, int out_size, void* d_ws, size_t ws_size,
                              hipStream_t stream) {
    const float* x     = (const float*)d_in[0];
    const float* Wq    = (const float*)d_in[1];
    const float* Wk    = (const float*)d_in[2];
    const float* Wv    = (const float*)d_in[3];
    const float* Wm    = (const float*)d_in[4];
    const float* W1    = (const float*)d_in[5];
    const float* b1    = (const float*)d_in[6];
    const float* W2    = (const float*)d_in[7];
    const float* b2    = (const float*)d_in[8];
    const float* g_att = (const float*)d_in[9];
    const float* b_att = (const float*)d_in[10];
    const float* g_ffn = (const float*)d_in[11];
    const float* b_ffn = (const float*)d_in[12];
    float* out = (float*)d_out;

    // Workspace map (live ranges disjoint in time)
    char* ws = (char*)d_ws;
    u16*   Wqkvt = (u16*)(ws);                    // 1.5 MB
    u16*   Wmt   = (u16*)(ws + 0x180000);         // 0.5 MB
    u16*   W1t   = (u16*)(ws + 0x200000);         // 0.5 MB
    u16*   W2t   = (u16*)(ws + 0x280000);         // 0.5 MB
    float* KV    = (float*)(ws + 0x300000);       // 512 KB
    float* Ksum  = (float*)(ws + 0x380000);       // 16 KB
    u16*   hb    = (u16*)(ws + 0x400000);         // 32 MB (LN1 out; reused as msg)
    float* Pkv   = (float*)(ws + 0x400000);       // 16 MB, aliases hb (hb dead in step 4)
    float* PKsum = (float*)(ws + 0x1400000);      // 512 KB
    u16*   qkv   = (u16*)(ws + 0x2400000);        // 96 MB
    u16*   h2    = qkv;                           // 32 MB (qkv dead after step 5)
    u16*   f1    = (u16*)(ws + 0x4400000);        // 32 MB (in qkv tail, dead by step 8)

    // 1. weights -> bf16 transposed
    prep_weights<<<6 * 64, 256, 0, stream>>>(Wq, Wk, Wv, Wm, W1, W2,
                                             Wqkvt, Wmt, W1t, W2t);
    // 2. LN1
    ln_kernel<<<ROWS / 4, 256, 0, stream>>>(x, g_att, b_att, hb);
    // 3. qkv = h @ [Wq|Wk|Wv] with feature-map epilogue (barrier-free wave-stream GEMM)
    gemm_stream<0><<<3072, 512, 0, stream>>>(hb, Wqkvt, 1536, 24,
                                             qkv, nullptr, nullptr, nullptr);
    // 4. KV/Ksum: MFMA partials + final reduce (no atomics, no memset)
    kv_reduce<<<dim3(128, 8), 256, 0, stream>>>(qkv, Pkv, PKsum);
    kv_final<<<512, 256, 0, stream>>>(Pkv, PKsum, KV, Ksum);
    // 5. msg (overwrites hb region - Pkv already consumed)
    msg_kernel<<<1024, 256, 0, stream>>>(qkv, KV, Ksum, hb);
    // 6. x2 = x + msg @ Wm   (x2 lives in d_out)
    gemm_tile<1><<<4 * 256, 256, 0, stream>>>(hb, Wmt, 512, 512, 4,
                                              nullptr, out, nullptr, x);
    // 7. LN2
    ln_kernel<<<ROWS / 4, 256, 0, stream>>>(out, g_ffn, b_ffn, h2);
    // 8. f1 = gelu(h2 @ W1 + b1)
    gemm_tile<2><<<4 * 256, 256, 0, stream>>>(h2, W1t, 512, 512, 4,
                                              f1, nullptr, b1, nullptr);
    // 9. out = x2 + f1 @ W2 + b2   (in place on d_out)
    gemm_tile<3><<<4 * 256, 256, 0, stream>>>(f1, W2t, 512, 512, 4,
                                              nullptr, out, b2, nullptr);
}

// Round 6
// 383.118 us; speedup vs baseline: 1.1043x; 1.0243x over previous
//
#include <hip/hip_runtime.h>
#include <hip/hip_bf16.h>
#include <math.h>

typedef unsigned short u16;
typedef __attribute__((ext_vector_type(8))) __bf16 bf16x8;
typedef __attribute__((ext_vector_type(4))) float floatx4;

#define SEQ   4096
#define BATCH 8
#define ROWS  32768   // BATCH*SEQ
#define C     512
#define NH    16
#define HD    32

__device__ inline u16 f2bf(float f) {
    union { float f; unsigned u; } v; v.f = f;
    unsigned r = (v.u + 0x7FFFu + ((v.u >> 16) & 1u)) >> 16;
    return (u16)r;
}
__device__ inline float bf2f(u16 h) {
    union { unsigned u; float f; } v; v.u = ((unsigned)h) << 16;
    return v.f;
}

// async global -> LDS, 16B per lane; lds ptr must be wave-uniform (HW adds lane*16)
__device__ inline void g2lds16(const u16* g, u16* l) {
    __builtin_amdgcn_global_load_lds((const __attribute__((address_space(1))) unsigned*)g,
                                     (__attribute__((address_space(3))) unsigned*)l, 16, 0, 0);
}

// ---------------- weight prep: fp32 (k,n) -> bf16 transposed (n,k), 64x64 LDS tiles ----------------
__global__ __launch_bounds__(256) void prep_weights(
    const float* __restrict__ Wq, const float* __restrict__ Wk,
    const float* __restrict__ Wv, const float* __restrict__ Wm,
    const float* __restrict__ W1, const float* __restrict__ W2,
    u16* __restrict__ Wqkvt, u16* __restrict__ Wmt,
    u16* __restrict__ W1t, u16* __restrict__ W2t)
{
    int blk = blockIdx.x;                 // 6 mats * 64 tiles
    int mat = blk >> 6;
    int tile = blk & 63;
    int k0 = (tile >> 3) * 64, n0 = (tile & 7) * 64;
    const float* src; u16* dst;
    switch (mat) {
        case 0: src = Wq; dst = Wqkvt;              break;
        case 1: src = Wk; dst = Wqkvt + 512*512;    break;
        case 2: src = Wv; dst = Wqkvt + 2*512*512;  break;
        case 3: src = Wm; dst = Wmt;                break;
        case 4: src = W1; dst = W1t;                break;
        default: src = W2; dst = W2t;               break;
    }
    __shared__ float ts[64][65];
    int t = threadIdx.x;
    #pragma unroll
    for (int i = 0; i < 16; i++) {
        int e = i * 256 + t;
        int kr = e >> 6, nc = e & 63;
        ts[kr][nc] = src[(size_t)(k0 + kr) * 512 + n0 + nc];   // coalesced 256B rows
    }
    __syncthreads();
    #pragma unroll
    for (int i = 0; i < 2; i++) {
        int e = i * 256 + t;                 // 512 chunks of 8
        int nr = e >> 3, kc0 = (e & 7) * 8;
        union { uint4 v; u16 u[8]; } o;
        #pragma unroll
        for (int q = 0; q < 8; q++) o.u[q] = f2bf(ts[kc0 + q][nr]);
        *(uint4*)(dst + (size_t)(n0 + nr) * 512 + k0 + kc0) = o.v;   // coalesced 16B stores
    }
}

// ---------------- layernorm: fp32 in -> bf16 out, one wave per row ----------------
__global__ __launch_bounds__(256) void ln_kernel(
    const float* __restrict__ in, const float* __restrict__ g,
    const float* __restrict__ b, u16* __restrict__ out)
{
    int row  = blockIdx.x * 4 + (threadIdx.x >> 6);
    int lane = threadIdx.x & 63;
    const float* p = in + (size_t)row * C + lane * 8;
    float4 v0 = *(const float4*)p;
    float4 v1 = *(const float4*)(p + 4);
    float s  = v0.x + v0.y + v0.z + v0.w + v1.x + v1.y + v1.z + v1.w;
    float s2 = v0.x*v0.x + v0.y*v0.y + v0.z*v0.z + v0.w*v0.w
             + v1.x*v1.x + v1.y*v1.y + v1.z*v1.z + v1.w*v1.w;
    #pragma unroll
    for (int off = 1; off < 64; off <<= 1) {
        s  += __shfl_xor(s, off);
        s2 += __shfl_xor(s2, off);
    }
    float mean = s * (1.f / C);
    float var  = s2 * (1.f / C) - mean * mean;
    float inv  = rsqrtf(var + 1e-6f);
    int c = lane * 8;
    float4 g0 = *(const float4*)(g + c), g1 = *(const float4*)(g + c + 4);
    float4 b0 = *(const float4*)(b + c), b1 = *(const float4*)(b + c + 4);
    union { uint4 v; u16 u[8]; } o;
    o.u[0] = f2bf((v0.x - mean) * inv * g0.x + b0.x);
    o.u[1] = f2bf((v0.y - mean) * inv * g0.y + b0.y);
    o.u[2] = f2bf((v0.z - mean) * inv * g0.z + b0.z);
    o.u[3] = f2bf((v0.w - mean) * inv * g0.w + b0.w);
    o.u[4] = f2bf((v1.x - mean) * inv * g1.x + b1.x);
    o.u[5] = f2bf((v1.y - mean) * inv * g1.y + b1.y);
    o.u[6] = f2bf((v1.z - mean) * inv * g1.z + b1.z);
    o.u[7] = f2bf((v1.w - mean) * inv * g1.w + b1.w);
    *(uint4*)(out + (size_t)row * C + c) = o.v;
}

// ---------------- bf16 MFMA GEMM, 128x128 tile (proven structure, grouped XCD swizzle) ----------
// Grouped swizzle (R5-validated on all GEMMs): block g -> XCD g&7; within an XCD, sweep
// x-major over groups of 2 y-tiles. A-group (2 tiles) + whole B panel stay L2-resident ->
// A HBM-fetched ~once (gemm_stream R5: FETCH 40MB vs 85MB with the old per-XCD-panel sweep).
template <int EPI>
__global__ __launch_bounds__(256, 2) void gemm_tile(
    const u16* __restrict__ A, const u16* __restrict__ Bt,
    int K, int ldc, int nx, int ypx,
    u16* __restrict__ outb, float* __restrict__ outf,
    const float* __restrict__ bias, const float* __restrict__ resid)
{
    __shared__ u16 lsA[128 * 64];
    __shared__ u16 lsB[128 * 64];
    const int t = threadIdx.x;
    const int w = t >> 6, l = t & 63, lr = l & 15, quad = l >> 4;
    // grouped XCD swizzle: 2 y-tiles per group, x-major inside the group
    const int g = blockIdx.x;
    const int xcd = g & 7;
    const int q = g >> 3;
    const int npg = nx * 2;
    const int grp = q / npg, rem = q - grp * npg;
    const int tx = rem >> 1;
    const int ty = xcd * ypx + grp * 2 + (rem & 1);
    const int m0 = ty * 128, n0 = tx * 128;
    const int RW = (w >> 1) * 64, CW = (w & 1) * 64;

    floatx4 acc[4][4];
    #pragma unroll
    for (int i = 0; i < 4; i++)
        #pragma unroll
        for (int j = 0; j < 4; j++) { floatx4 z = {0.f, 0.f, 0.f, 0.f}; acc[i][j] = z; }

    const int srow = w * 32 + (l >> 3);
    const int scol = (((l & 7) - (l >> 3)) & 7) * 8;      // row&7 == l>>3 here
    const u16* Ag = A  + (size_t)(m0 + srow) * K + scol;
    const u16* Bg = Bt + (size_t)(n0 + srow) * K + scol;
    u16* lAw = lsA + w * 2048;
    u16* lBw = lsB + w * 2048;

    for (int kk = 0; kk < K; kk += 64) {
        __syncthreads();
        #pragma unroll
        for (int c = 0; c < 4; c++) {
            g2lds16(Ag + (size_t)(c * 8) * K + kk, lAw + c * 512);
            g2lds16(Bg + (size_t)(c * 8) * K + kk, lBw + c * 512);
        }
        __syncthreads();
        #pragma unroll
        for (int ks = 0; ks < 2; ks++) {
            bf16x8 af[4], bfr[4];
            const int m = ((ks * 4 + quad + (lr & 7)) & 7) * 8;
            #pragma unroll
            for (int i = 0; i < 4; i++) {
                af[i]  = *(const bf16x8*)(lsA + (RW + i * 16 + lr) * 64 + m);
                bfr[i] = *(const bf16x8*)(lsB + (CW + i * 16 + lr) * 64 + m);
            }
            #pragma unroll
            for (int i = 0; i < 4; i++)
                #pragma unroll
                for (int j = 0; j < 4; j++)
                    acc[i][j] = __builtin_amdgcn_mfma_f32_16x16x32_bf16(af[i], bfr[j], acc[i][j], 0, 0, 0);
        }
    }

    #pragma unroll
    for (int i = 0; i < 4; i++) {
        #pragma unroll
        for (int j = 0; j < 4; j++) {
            #pragma unroll
            for (int r = 0; r < 4; r++) {
                int row = m0 + RW + i * 16 + quad * 4 + r;
                int col = n0 + CW + j * 16 + lr;
                float v = acc[i][j][r];
                size_t idx = (size_t)row * ldc + col;
                if constexpr (EPI == 0) {
                    if (col < 1024) v = v > 0.f ? v + 1.f : __expf(v);
                    else            v *= (1.0f / SEQ);
                    outb[idx] = f2bf(v);
                } else if constexpr (EPI == 1) {
                    outf[idx] = resid[idx] + v;
                } else if constexpr (EPI == 2) {
                    v += bias[col];
                    v = 0.5f * v * (1.f + erff(v * 0.70710678118f));
                    outb[idx] = f2bf(v);
                } else {
                    outf[idx] = outf[idx] + v + bias[col];
                }
            }
        }
    }
}

// ---------------- KV partials via MFMA: per-wave private LDS tiles, no atomics ----------------
__global__ __launch_bounds__(256) void kv_reduce(
    const u16* __restrict__ qkv, float* __restrict__ Pkv, float* __restrict__ PKsum)
{
    const int bh = blockIdx.x;            // 0..127
    const int b = bh >> 4, h = bh & 15;
    const int chunk = blockIdx.y;         // 0..7
    const int t = threadIdx.x;
    const int w = t >> 6, l = t & 63, lr = l & 15, quad = l >> 4;
    __shared__ u16 lds[4 * 2 * 2048];     // [wave][buf][K 1024 | V 1024] = 32 KB

    const int sbase = chunk * 512 + w * 128;
    const u16* qbase = qkv + (size_t)b * SEQ * 1536 + 512 + h * HD;  // K part; V = +512

    const int sl0 = l >> 2;               // rows 0..15 (instr 0)
    const int sl1 = 16 + sl0;             // rows 16..31 (instr 1)
    const int cl  = l & 3;
    const int cg0 = (cl + (sl0 >> 3)) & 3;
    const int cg1 = (cl + (sl1 >> 3)) & 3;
    const int gof0 = sl0 * 1536 + cg0 * 8;
    const int gof1 = sl1 * 1536 + cg1 * 8;

    u16* myl = lds + w * 4096;

    const int offA0 = quad * 256 + ((((lr >> 3) + 0) - quad) & 3) * 8 + (lr & 7);  // d 0..15
    const int offA1 = quad * 256 + ((((lr >> 3) + 2) - quad) & 3) * 8 + (lr & 7);  // d 16..31

    floatx4 a00 = {0,0,0,0}, a01 = {0,0,0,0}, a10 = {0,0,0,0}, a11 = {0,0,0,0};
    float ks0 = 0.f, ks1 = 0.f;

    {
        const u16* gK = qbase + (size_t)sbase * 1536;
        g2lds16(gK + gof0,       myl);
        g2lds16(gK + gof1,       myl + 512);
        g2lds16(gK + 512 + gof0, myl + 1024);
        g2lds16(gK + 512 + gof1, myl + 1536);
    }
    #pragma unroll
    for (int st = 0; st < 4; st++) {
        if (st < 3) {                      // prefetch next buf before the drain
            const u16* gK = qbase + (size_t)(sbase + (st + 1) * 32) * 1536;
            u16* nl = myl + ((st + 1) & 1) * 2048;
            g2lds16(gK + gof0,       nl);
            g2lds16(gK + gof1,       nl + 512);
            g2lds16(gK + 512 + gof0, nl + 1024);
            g2lds16(gK + 512 + gof1, nl + 1536);
        }
        __syncthreads();                   // vmcnt(0) drain, compiler-safe fence
        const u16* lK = myl + (st & 1) * 2048;
        const u16* lV = lK + 1024;
        union { bf16x8 v; u16 u[8]; } fa0, fa1, fb0, fb1;
        #pragma unroll
        for (int j = 0; j < 8; j++) {
            fa0.u[j] = lK[offA0 + j * 32];
            fa1.u[j] = lK[offA1 + j * 32];
            fb0.u[j] = lV[offA0 + j * 32];
            fb1.u[j] = lV[offA1 + j * 32];
        }
        #pragma unroll
        for (int j = 0; j < 8; j++) { ks0 += bf2f(fa0.u[j]); ks1 += bf2f(fa1.u[j]); }
        a00 = __builtin_amdgcn_mfma_f32_16x16x32_bf16(fa0.v, fb0.v, a00, 0, 0, 0);
        a01 = __builtin_amdgcn_mfma_f32_16x16x32_bf16(fa0.v, fb1.v, a01, 0, 0, 0);
        a10 = __builtin_amdgcn_mfma_f32_16x16x32_bf16(fa1.v, fb0.v, a10, 0, 0, 0);
        a11 = __builtin_amdgcn_mfma_f32_16x16x32_bf16(fa1.v, fb1.v, a11, 0, 0, 0);
    }

    const int p = bh * 32 + chunk * 4 + w;
    float* dst = Pkv + (size_t)p * 1024;
    floatx4 accs[2][2] = {{a00, a01}, {a10, a11}};
    #pragma unroll
    for (int i = 0; i < 2; i++)
        #pragma unroll
        for (int j = 0; j < 2; j++)
            #pragma unroll
            for (int r = 0; r < 4; r++)
                dst[(i * 16 + quad * 4 + r) * 32 + j * 16 + lr] = accs[i][j][r];

    float k0 = ks0 + __shfl_xor(ks0, 16); k0 += __shfl_xor(k0, 32);
    float k1 = ks1 + __shfl_xor(ks1, 16); k1 += __shfl_xor(k1, 32);
    if (quad == 0) {
        PKsum[p * 32 + lr]      = k0;
        PKsum[p * 32 + 16 + lr] = k1;
    }
}

// ---------------- final reduce: 512 blocks (128 bh x 4 parts) ----------------
__global__ __launch_bounds__(256) void kv_final(
    const float* __restrict__ Pkv, const float* __restrict__ PKsum,
    float* __restrict__ KV, float* __restrict__ Ksum)
{
    const int blk = blockIdx.x;          // 512 = 128 bh x 4 parts
    const int bh = blk >> 2, part = blk & 3;
    const int t = threadIdx.x;
    const float* src = Pkv + (size_t)bh * 32 * 1024 + part * 256 + t;
    float a = 0.f;
    #pragma unroll 4
    for (int p = 0; p < 32; p++) a += src[(size_t)p * 1024];
    KV[(size_t)bh * 1024 + part * 256 + t] = a;
    if (part == 0 && t < 32) {
        float s = 0.f;
        for (int p = 0; p < 32; p++) s += PKsum[(bh * 32 + p) * 32 + t];
        Ksum[bh * 32 + t] = s;
    }
}

// ---------------- msg = (Q . KV) * SEQ / (Q . Ksum + eps) ----------------
__global__ __launch_bounds__(256) void msg_kernel(
    const u16* __restrict__ qkv, const float* __restrict__ KV,
    const float* __restrict__ Ksum, u16* __restrict__ msg)
{
    int blk = blockIdx.x;           // 1024 blocks
    int b = blk >> 7;
    int r0 = (blk & 127) * 32;
    int t = threadIdx.x;
    int h = t >> 4;
    int vd = (t & 15) * 2;
    float kv0[32], kv1[32], ksr[32];
    const float* kvh = KV + ((size_t)b * 16 + h) * 1024;
    const float* ksh = Ksum + (b * 16 + h) * 32;
    #pragma unroll
    for (int d = 0; d < 32; d++) {
        kv0[d] = kvh[d * 32 + vd];
        kv1[d] = kvh[d * 32 + vd + 1];
        ksr[d] = ksh[d];
    }
    __shared__ u16 Qs[4 * 512];
    const int srr = t >> 6;
    const int scc = (t & 63) * 8;
    for (int rg = 0; rg < 32; rg += 4) {
        size_t row = (size_t)b * SEQ + r0 + rg;
        uint4 qv = *(const uint4*)(qkv + (row + srr) * 1536 + scc);
        __syncthreads();
        *(uint4*)(Qs + srr * 512 + scc) = qv;
        __syncthreads();
        #pragma unroll
        for (int r2 = 0; r2 < 4; r2++) {
            const u16* qp = Qs + r2 * 512 + h * HD;
            float q[32];
            #pragma unroll
            for (int i0 = 0; i0 < 32; i0 += 8) {
                union { uint4 v; u16 u[8]; } uu;
                uu.v = *(const uint4*)(qp + i0);
                #pragma unroll
                for (int jq = 0; jq < 8; jq++) q[i0 + jq] = bf2f(uu.u[jq]);
            }
            float zdot = 0.f, m0 = 0.f, m1 = 0.f;
            #pragma unroll
            for (int d = 0; d < 32; d++) {
                float qd = q[d];
                zdot += qd * ksr[d];
                m0   += qd * kv0[d];
                m1   += qd * kv1[d];
            }
            float z = (float)SEQ / (zdot + 1e-6f);
            unsigned pack = (unsigned)f2bf(m0 * z) | ((unsigned)f2bf(m1 * z) << 16);
            *(unsigned*)(msg + (row + r2) * C + h * HD + vd) = pack;
        }
    }
}

extern "C" void kernel_launch(void* const* d_in, const int* in_sizes, int n_in,
                              void* d_out, int out_size, void* d_ws, size_t ws_size,
                              hipStream_t stream) {
    const float* x     = (const float*)d_in[0];
    const float* Wq    = (const float*)d_in[1];
    const float* Wk    = (const float*)d_in[2];
    const float* Wv    = (const float*)d_in[3];
    const float* Wm    = (const float*)d_in[4];
    const float* W1    = (const float*)d_in[5];
    const float* b1    = (const float*)d_in[6];
    const float* W2    = (const float*)d_in[7];
    const float* b2    = (const float*)d_in[8];
    const float* g_att = (const float*)d_in[9];
    const float* b_att = (const float*)d_in[10];
    const float* g_ffn = (const float*)d_in[11];
    const float* b_ffn = (const float*)d_in[12];
    float* out = (float*)d_out;

    // Workspace map (live ranges disjoint in time)
    char* ws = (char*)d_ws;
    u16*   Wqkvt = (u16*)(ws);                    // 1.5 MB
    u16*   Wmt   = (u16*)(ws + 0x180000);         // 0.5 MB
    u16*   W1t   = (u16*)(ws + 0x200000);         // 0.5 MB
    u16*   W2t   = (u16*)(ws + 0x280000);         // 0.5 MB
    float* KV    = (float*)(ws + 0x300000);       // 512 KB
    float* Ksum  = (float*)(ws + 0x380000);       // 16 KB
    u16*   hb    = (u16*)(ws + 0x400000);         // 32 MB (LN1 out; reused as msg)
    float* Pkv   = (float*)(ws + 0x400000);       // 16 MB, aliases hb (hb dead in step 4)
    float* PKsum = (float*)(ws + 0x1400000);      // 512 KB
    u16*   qkv   = (u16*)(ws + 0x2400000);        // 96 MB
    u16*   h2    = qkv;                           // 32 MB (qkv dead after step 5)
    u16*   f1    = (u16*)(ws + 0x4400000);        // 32 MB (in qkv tail, dead by step 8)

    // 1. weights -> bf16 transposed
    prep_weights<<<6 * 64, 256, 0, stream>>>(Wq, Wk, Wv, Wm, W1, W2,
                                             Wqkvt, Wmt, W1t, W2t);
    // 2. LN1
    ln_kernel<<<ROWS / 4, 256, 0, stream>>>(x, g_att, b_att, hb);
    // 3. qkv = h @ [Wq|Wk|Wv]  (proven gemm_tile + grouped swizzle; 3072 blocks, 256 y x 12 x)
    gemm_tile<0><<<3072, 256, 0, stream>>>(hb, Wqkvt, 512, 1536, 12, 32,
                                           qkv, nullptr, nullptr, nullptr);
    // 4. KV/Ksum: MFMA partials + final reduce (no atomics, no memset)
    kv_reduce<<<dim3(128, 8), 256, 0, stream>>>(qkv, Pkv, PKsum);
    kv_final<<<512, 256, 0, stream>>>(Pkv, PKsum, KV, Ksum);
    // 5. msg (overwrites hb region - Pkv already consumed)
    msg_kernel<<<1024, 256, 0, stream>>>(qkv, KV, Ksum, hb);
    // 6. x2 = x + msg @ Wm   (x2 lives in d_out)
    gemm_tile<1><<<1024, 256, 0, stream>>>(hb, Wmt, 512, 512, 4, 32,
                                           nullptr, out, nullptr, x);
    // 7. LN2
    ln_kernel<<<ROWS / 4, 256, 0, stream>>>(out, g_ffn, b_ffn, h2);
    // 8. f1 = gelu(h2 @ W1 + b1)
    gemm_tile<2><<<1024, 256, 0, stream>>>(h2, W1t, 512, 512, 4, 32,
                                           f1, nullptr, b1, nullptr);
    // 9. out = x2 + f1 @ W2 + b2   (in place on d_out)
    gemm_tile<3><<<1024, 256, 0, stream>>>(f1, W2t, 512, 512, 4, 32,
                                           nullptr, out, b2, nullptr);
}